// Round 2
// baseline (29406.934 us; speedup 1.0000x reference)
//
#include <hip/hip_runtime.h>
#include <cstdint>
#include <cmath>

#define BB 64
#define TT 512
#define NI 256
#define HH 1024
#define NO 512
#define NSTEPS 100
#define KT 64
#define NBLK 256
#define NTHR 256

// ---- persistent device-global state (module-owned; NOT in d_ws) ----
__device__ unsigned g_cnt;
__device__ float g_hA[HH * BB];
__device__ float g_hB[HH * BB];
__device__ float g_cst[HH * BB];
__device__ float g_dsum[4 * HH];
__device__ float g_logits[NO * BB];
__device__ float g_xt[TT * NI * BB];   // x transposed to [t][k][b]

__device__ __forceinline__ float sigf(float x) { return 1.0f / (1.0f + expf(-x)); }

// Monotonic grid barrier (ockl grid-sync pattern): agent-scope fences give
// cross-XCD visibility (L2 wb/inv); __syncthreads drains vmcnt first.
__device__ __forceinline__ void grid_sync(unsigned* cnt, unsigned target) {
  __syncthreads();
  if (threadIdx.x == 0) {
    __builtin_amdgcn_fence(__ATOMIC_RELEASE, "agent");
    __hip_atomic_fetch_add(cnt, 1u, __ATOMIC_RELAXED, __HIP_MEMORY_SCOPE_AGENT);
    while (__hip_atomic_load(cnt, __ATOMIC_RELAXED, __HIP_MEMORY_SCOPE_AGENT) < target) {
      __builtin_amdgcn_s_sleep(2);
    }
    __builtin_amdgcn_fence(__ATOMIC_ACQUIRE, "agent");
  }
  __syncthreads();
}

__global__ void reset_counter() { g_cnt = 0u; }

__global__ void __launch_bounds__(NTHR, 1)
seq2seq_kernel(const float* __restrict__ xin,
               const float* __restrict__ eWih, const float* __restrict__ eWhh,
               const float* __restrict__ ebih, const float* __restrict__ ebhh,
               const float* __restrict__ dWih, const float* __restrict__ dWhh,
               const float* __restrict__ dbih, const float* __restrict__ dbhh,
               const float* __restrict__ fcW,  const float* __restrict__ fcb,
               int* __restrict__ out)
{
  __shared__ __align__(16) float As[KT][BB];        // A tile, transposed [k][b]
  __shared__ __align__(16) float Ws[16][KT + 4];    // 16 weight rows (4 gates x 4 j)
  __shared__ __align__(16) float Gs[16][KT + 4];    // gate partials [g*4+jj][b]
  __shared__ __align__(16) float Wf[4][KT + 4];     // fc_W rows for logits
  __shared__ float avals[4][BB];
  __shared__ int   aidx[4][BB];
  __shared__ float ptok[BB];

  const int tid = threadIdx.x;
  const int blk = blockIdx.x;
  unsigned sync_no = 0;
  unsigned* cnt = &g_cnt;

  // accumulate-phase mapping: thread = (gate g_, column jj, batch-group bg of 4)
  const int g_ = tid & 3;
  const int jj = (tid >> 2) & 3;
  const int bg = tid >> 4;            // 0..15
  const int rt = g_ * 4 + jj;         // LDS weight row
  // combine-phase mapping: thread = (column jj2, batch cb)
  const int jj2 = tid >> 6;           // 0..3
  const int cb  = tid & 63;
  const int j2  = blk * 4 + jj2;      // global hidden index

  // ---------------- init ----------------
  {
    int idx = blk * NTHR + tid;       // 65536 == HH*BB
    g_hA[idx]  = 0.0f;
    g_cst[idx] = 0.0f;
    // rowsum(dec_Wih): decoder input is token value broadcast over all NO features
    int r = blk * 16 + (tid >> 4);
    int l16 = tid & 15;
    const float* wr = dWih + (size_t)r * NO;
    float s = 0.0f;
    for (int k = l16; k < NO; k += 16) s += wr[k];
    for (int off = 8; off; off >>= 1) s += __shfl_down(s, off, 16);
    if (l16 == 0) g_dsum[r] = s;
    // transpose x: xt[t][k][b] = x[b][t][k]
    for (int w = blk * NTHR + tid; w < TT * NI * BB; w += NBLK * NTHR) {
      int b = w & 63;
      int tk = w >> 6;
      int k = tk & (NI - 1);
      int t = tk >> 8;
      g_xt[w] = xin[((size_t)b * TT + t) * NI + k];
    }
  }
  grid_sync(cnt, ++sync_no * NBLK);

  const float* hc = g_hA;
  float* hn = g_hB;

  // ---------------- encoder: 512 steps ----------------
  for (int t = 0; t < TT; ++t) {
    float a0 = 0.f, a1 = 0.f, a2 = 0.f, a3 = 0.f;
    for (int ch = 0; ch < 20; ++ch) {
      const int k0 = ch * KT;
      __syncthreads();
      // ---- stage A tile (transposed [kk][b]) ----
      {
        const float* asrc = (ch < 4) ? (g_xt + ((size_t)t * NI + k0) * BB)
                                     : (hc + (size_t)(k0 - NI) * BB);
        #pragma unroll
        for (int i = 0; i < 4; ++i) {
          int fi = tid + i * NTHR;
          int kk = fi >> 4, c4 = (fi & 15) * 4;
          *(float4*)&As[kk][c4] = *(const float4*)&asrc[kk * BB + c4];
        }
      }
      // ---- stage W tile: 16 rows x 64 ----
      {
        const float* wsrc = (ch < 4) ? eWih : eWhh;
        const int ld  = (ch < 4) ? NI : HH;
        const int wk0 = (ch < 4) ? k0 : k0 - NI;
        int row = tid >> 4, c4 = (tid & 15) * 4;
        int grow = (row >> 2) * HH + blk * 4 + (row & 3);
        *(float4*)&Ws[row][c4] = *(const float4*)&wsrc[(size_t)grow * ld + wk0 + c4];
      }
      __syncthreads();
      #pragma unroll
      for (int kk = 0; kk < KT; ++kk) {
        float4 a = *(const float4*)&As[kk][bg * 4];
        float w = Ws[rt][kk];
        a0 = fmaf(a.x, w, a0);
        a1 = fmaf(a.y, w, a1);
        a2 = fmaf(a.z, w, a2);
        a3 = fmaf(a.w, w, a3);
      }
    }
    { float4 v; v.x = a0; v.y = a1; v.z = a2; v.w = a3;
      *(float4*)&Gs[rt][bg * 4] = v; }
    __syncthreads();
    {
      float pi = Gs[0 + jj2][cb]  + ebih[j2]          + ebhh[j2];
      float pf = Gs[4 + jj2][cb]  + ebih[HH + j2]     + ebhh[HH + j2];
      float pg = Gs[8 + jj2][cb]  + ebih[2 * HH + j2] + ebhh[2 * HH + j2];
      float po = Gs[12 + jj2][cb] + ebih[3 * HH + j2] + ebhh[3 * HH + j2];
      float co = g_cst[(size_t)j2 * BB + cb];
      float cn = sigf(pf) * co + sigf(pi) * tanhf(pg);
      float hv = sigf(po) * tanhf(cn);
      g_cst[(size_t)j2 * BB + cb] = cn;
      hn[(size_t)j2 * BB + cb] = hv;
    }
    grid_sync(cnt, ++sync_no * NBLK);
    float* tmp = (float*)hc; hc = hn; hn = tmp;
  }

  // ---------------- decoder: 100 steps ----------------
  if (tid < BB) ptok[tid] = 0.0f;
  __syncthreads();

  for (int s = 0; s < NSTEPS; ++s) {
    // ---- D1: LSTM cell (K = HH; token term folded via g_dsum) ----
    float a0 = 0.f, a1 = 0.f, a2 = 0.f, a3 = 0.f;
    for (int ch = 0; ch < 16; ++ch) {
      const int k0 = ch * KT;
      __syncthreads();
      const float* asrc = hc + (size_t)k0 * BB;
      #pragma unroll
      for (int i = 0; i < 4; ++i) {
        int fi = tid + i * NTHR;
        int kk = fi >> 4, c4 = (fi & 15) * 4;
        *(float4*)&As[kk][c4] = *(const float4*)&asrc[kk * BB + c4];
      }
      {
        int row = tid >> 4, c4 = (tid & 15) * 4;
        int grow = (row >> 2) * HH + blk * 4 + (row & 3);
        *(float4*)&Ws[row][c4] = *(const float4*)&dWhh[(size_t)grow * HH + k0 + c4];
      }
      __syncthreads();
      #pragma unroll
      for (int kk = 0; kk < KT; ++kk) {
        float4 a = *(const float4*)&As[kk][bg * 4];
        float w = Ws[rt][kk];
        a0 = fmaf(a.x, w, a0);
        a1 = fmaf(a.y, w, a1);
        a2 = fmaf(a.z, w, a2);
        a3 = fmaf(a.w, w, a3);
      }
    }
    { float4 v; v.x = a0; v.y = a1; v.z = a2; v.w = a3;
      *(float4*)&Gs[rt][bg * 4] = v; }
    __syncthreads();
    {
      float tk = ptok[cb];
      float pi = Gs[0 + jj2][cb]  + dbih[j2]          + dbhh[j2]          + tk * g_dsum[j2];
      float pf = Gs[4 + jj2][cb]  + dbih[HH + j2]     + dbhh[HH + j2]     + tk * g_dsum[HH + j2];
      float pg = Gs[8 + jj2][cb]  + dbih[2 * HH + j2] + dbhh[2 * HH + j2] + tk * g_dsum[2 * HH + j2];
      float po = Gs[12 + jj2][cb] + dbih[3 * HH + j2] + dbhh[3 * HH + j2] + tk * g_dsum[3 * HH + j2];
      float co = g_cst[(size_t)j2 * BB + cb];
      float cn = sigf(pf) * co + sigf(pi) * tanhf(pg);
      float hv = sigf(po) * tanhf(cn);
      g_cst[(size_t)j2 * BB + cb] = cn;
      hn[(size_t)j2 * BB + cb] = hv;
    }
    grid_sync(cnt, ++sync_no * NBLK);
    { float* tmp = (float*)hc; hc = hn; hn = tmp; }   // hc = new h

    // ---- D2: logits = h @ fc_W^T + fc_b (blocks 0..127, 4 o-rows each) ----
    if (blk < 128) {
      const int oo = tid >> 6, ob = tid & 63;
      const int o = blk * 4 + oo;
      float acc = 0.0f;
      for (int ch = 0; ch < 16; ++ch) {
        const int k0 = ch * KT;
        __syncthreads();
        const float* asrc = hc + (size_t)k0 * BB;
        #pragma unroll
        for (int i = 0; i < 4; ++i) {
          int fi = tid + i * NTHR;
          int kk = fi >> 4, c4 = (fi & 15) * 4;
          *(float4*)&As[kk][c4] = *(const float4*)&asrc[kk * BB + c4];
        }
        { int row = tid >> 6, col = tid & 63;
          Wf[row][col] = fcW[(size_t)(blk * 4 + row) * HH + k0 + col]; }
        __syncthreads();
        #pragma unroll
        for (int kk = 0; kk < KT; ++kk)
          acc = fmaf(As[kk][ob], Wf[oo][kk], acc);
      }
      g_logits[(size_t)o * BB + ob] = acc + fcb[o];
    }
    grid_sync(cnt, ++sync_no * NBLK);

    // ---- argmax (redundant per block; first-index tie-break) ----
    {
      const int q = tid >> 6, b = tid & 63;
      float bv = -3.402823466e38f; int bo = 0;
      for (int o = q * 128; o < q * 128 + 128; ++o) {
        float v = g_logits[(size_t)o * BB + b];
        if (v > bv) { bv = v; bo = o; }
      }
      avals[q][b] = bv; aidx[q][b] = bo;
    }
    __syncthreads();
    if (tid < BB) {
      float bv = avals[0][tid]; int bo = aidx[0][tid];
      #pragma unroll
      for (int q = 1; q < 4; ++q)
        if (avals[q][tid] > bv) { bv = avals[q][tid]; bo = aidx[q][tid]; }
      ptok[tid] = (float)bo;
      if (blk == 0) out[(size_t)tid * NSTEPS + s] = bo;   // int32 tokens
    }
    __syncthreads();
  }
}

extern "C" void kernel_launch(void* const* d_in, const int* in_sizes, int n_in,
                              void* d_out, int out_size, void* d_ws, size_t ws_size,
                              hipStream_t stream) {
  (void)in_sizes; (void)n_in; (void)out_size; (void)d_ws; (void)ws_size;
  const float* xin  = (const float*)d_in[0];
  const float* eWih = (const float*)d_in[1];
  const float* eWhh = (const float*)d_in[2];
  const float* ebih = (const float*)d_in[3];
  const float* ebhh = (const float*)d_in[4];
  const float* dWih = (const float*)d_in[5];
  const float* dWhh = (const float*)d_in[6];
  const float* dbih = (const float*)d_in[7];
  const float* dbhh = (const float*)d_in[8];
  const float* fcW  = (const float*)d_in[9];
  const float* fcb  = (const float*)d_in[10];
  int* out = (int*)d_out;

  reset_counter<<<1, 1, 0, stream>>>();
  seq2seq_kernel<<<NBLK, NTHR, 0, stream>>>(
      xin, eWih, eWhh, ebih, ebhh, dWih, dWhh, dbih, dbhh, fcW, fcb, out);
}

// Round 3
// 22499.757 us; speedup vs baseline: 1.3070x; 1.3070x over previous
//
#include <hip/hip_runtime.h>
#include <cstdint>
#include <cmath>

#define BB 64
#define TT 512
#define NI 256
#define HH 1024
#define NO 512
#define NSTEPS 100
#define KT 64
#define NBLK 256
#define NTHR 256

// ---- persistent device-global state (module-owned; NOT in d_ws) ----
__device__ unsigned g_cnt;
__device__ float g_hA[HH * BB];
__device__ float g_hB[HH * BB];
__device__ float g_cst[HH * BB];
__device__ float g_dsum[4 * HH];
__device__ float g_logits[NO * BB];
__device__ float g_xt[TT * NI * BB];   // x transposed to [t][k][b]

__device__ __forceinline__ float sigf(float x) { return 1.0f / (1.0f + expf(-x)); }

// Monotonic grid barrier (ockl grid-sync pattern).
__device__ __forceinline__ void grid_sync(unsigned* cnt, unsigned target) {
  __syncthreads();
  if (threadIdx.x == 0) {
    __builtin_amdgcn_fence(__ATOMIC_RELEASE, "agent");
    __hip_atomic_fetch_add(cnt, 1u, __ATOMIC_RELAXED, __HIP_MEMORY_SCOPE_AGENT);
    while (__hip_atomic_load(cnt, __ATOMIC_RELAXED, __HIP_MEMORY_SCOPE_AGENT) < target) {
      __builtin_amdgcn_s_sleep(2);
    }
    __builtin_amdgcn_fence(__ATOMIC_ACQUIRE, "agent");
  }
  __syncthreads();
}

__global__ void reset_counter() { g_cnt = 0u; }

__global__ void __launch_bounds__(NTHR, 1)
seq2seq_kernel(const float* __restrict__ xin,
               const float* __restrict__ eWih, const float* __restrict__ eWhh,
               const float* __restrict__ ebih, const float* __restrict__ ebhh,
               const float* __restrict__ dWih, const float* __restrict__ dWhh,
               const float* __restrict__ dbih, const float* __restrict__ dbhh,
               const float* __restrict__ fcW,  const float* __restrict__ fcb,
               int* __restrict__ out)
{
  // A tile transposed [kk][b]; Wt transposed [kk][row] (row = gate*4 + jcol)
  __shared__ __align__(16) float As[KT][BB];          // 16 KB
  __shared__ __align__(16) float Wt[KT][20];          // 5 KB (16 rows + pad)
  __shared__ __align__(16) float Gp[16][17][68];      // 74 KB K-split partials
  __shared__ float avals[4][BB];
  __shared__ int   aidx[4][BB];
  __shared__ float ptok[BB];

  const int tid = threadIdx.x;
  const int blk = blockIdx.x;
  unsigned sync_no = 0;
  unsigned* cnt = &g_cnt;

  // main-GEMM thread mapping: 16 K-subgroups x (2 row-groups x 8 batch-groups)
  const int kt = tid >> 4;            // 0..15
  const int cg = tid & 7;             // batch group (x8)
  const int rg = (tid >> 3) & 1;      // row group (x8)
  // combine-phase mapping
  const int jj2 = tid >> 6;           // 0..3 (wave id)
  const int cb  = tid & 63;           // lane
  const int j2  = blk * 4 + jj2;      // global hidden index
  // fc-GEMM mapping: 32 K-subgroups x 8 batch-groups
  const int ktd = tid >> 3;           // 0..31
  const int cgd = tid & 7;
  float* const Gpd = &Gp[0][0][0];    // D2 partials alias: [32][276]

  // ---------------- init ----------------
  {
    int idx = blk * NTHR + tid;       // 65536 == HH*BB
    g_hA[idx]  = 0.0f;
    g_cst[idx] = 0.0f;
    int r = blk * 16 + (tid >> 4);
    int l16 = tid & 15;
    const float* wr = dWih + (size_t)r * NO;
    float s = 0.0f;
    for (int k = l16; k < NO; k += 16) s += wr[k];
    for (int off = 8; off; off >>= 1) s += __shfl_down(s, off, 16);
    if (l16 == 0) g_dsum[r] = s;
    for (int w = blk * NTHR + tid; w < TT * NI * BB; w += NBLK * NTHR) {
      int b = w & 63;
      int tk = w >> 6;
      int k = tk & (NI - 1);
      int t = tk >> 8;
      g_xt[w] = xin[((size_t)b * TT + t) * NI + k];
    }
  }
  grid_sync(cnt, ++sync_no * NBLK);

  const float* hc = g_hA;
  float* hn = g_hB;

  // ================ encoder: 512 steps ================
  for (int t = 0; t < TT; ++t) {
    float acc[8][8];
    #pragma unroll
    for (int r = 0; r < 8; ++r)
      #pragma unroll
      for (int c = 0; c < 8; ++c) acc[r][c] = 0.0f;

    for (int ch = 0; ch < 20; ++ch) {
      const int k0 = ch * KT;
      __syncthreads();
      // stage A tile [kk][b]
      {
        const float* asrc = (ch < 4) ? (g_xt + ((size_t)t * NI + k0) * BB)
                                     : (hc + (size_t)(k0 - NI) * BB);
        #pragma unroll
        for (int i = 0; i < 4; ++i) {
          int fi = tid + i * NTHR;
          int kk = fi >> 4, c4 = (fi & 15) * 4;
          *(float4*)&As[kk][c4] = *(const float4*)&asrc[kk * BB + c4];
        }
      }
      // stage W tile transposed: Wt[kk][row], row = gate*4 + jcol
      {
        const float* wsrc = (ch < 4) ? eWih : eWhh;
        const int ld  = (ch < 4) ? NI : HH;
        const int wk0 = (ch < 4) ? k0 : k0 - NI;
        int row = tid >> 4, c4 = (tid & 15) * 4;
        int grow = (row >> 2) * HH + blk * 4 + (row & 3);
        float4 wv = *(const float4*)&wsrc[(size_t)grow * ld + wk0 + c4];
        Wt[c4 + 0][row] = wv.x;
        Wt[c4 + 1][row] = wv.y;
        Wt[c4 + 2][row] = wv.z;
        Wt[c4 + 3][row] = wv.w;
      }
      __syncthreads();
      #pragma unroll
      for (int kk2 = 0; kk2 < 4; ++kk2) {
        const int kk = (kt << 2) | kk2;
        float4 a0 = *(const float4*)&As[kk][cg * 8];
        float4 a1 = *(const float4*)&As[kk][cg * 8 + 4];
        float4 w0 = *(const float4*)&Wt[kk][rg * 8];
        float4 w1 = *(const float4*)&Wt[kk][rg * 8 + 4];
        float av[8] = {a0.x, a0.y, a0.z, a0.w, a1.x, a1.y, a1.z, a1.w};
        float wv[8] = {w0.x, w0.y, w0.z, w0.w, w1.x, w1.y, w1.z, w1.w};
        #pragma unroll
        for (int r = 0; r < 8; ++r)
          #pragma unroll
          for (int c = 0; c < 8; ++c)
            acc[r][c] = fmaf(wv[r], av[c], acc[r][c]);
      }
    }
    // write K-split partials
    __syncthreads();
    #pragma unroll
    for (int r = 0; r < 8; ++r) {
      float4 v0 = {acc[r][0], acc[r][1], acc[r][2], acc[r][3]};
      float4 v1 = {acc[r][4], acc[r][5], acc[r][6], acc[r][7]};
      *(float4*)&Gp[kt][rg * 8 + r][cg * 8]     = v0;
      *(float4*)&Gp[kt][rg * 8 + r][cg * 8 + 4] = v1;
    }
    __syncthreads();
    // reduce + cell update: thread (jj2, cb)
    {
      float gsum[4];
      #pragma unroll
      for (int g = 0; g < 4; ++g) {
        const int rt = g * 4 + jj2;
        float s = 0.0f;
        #pragma unroll
        for (int q = 0; q < 16; ++q) s += Gp[q][rt][cb];
        gsum[g] = s;
      }
      float pi = gsum[0] + ebih[j2]          + ebhh[j2];
      float pf = gsum[1] + ebih[HH + j2]     + ebhh[HH + j2];
      float pg = gsum[2] + ebih[2 * HH + j2] + ebhh[2 * HH + j2];
      float po = gsum[3] + ebih[3 * HH + j2] + ebhh[3 * HH + j2];
      float co = g_cst[(size_t)j2 * BB + cb];
      float cn = sigf(pf) * co + sigf(pi) * tanhf(pg);
      float hv = sigf(po) * tanhf(cn);
      g_cst[(size_t)j2 * BB + cb] = cn;
      hn[(size_t)j2 * BB + cb] = hv;
    }
    grid_sync(cnt, ++sync_no * NBLK);
    float* tmp = (float*)hc; hc = hn; hn = tmp;
  }

  // ================ decoder: 100 steps ================
  if (tid < BB) ptok[tid] = 0.0f;
  __syncthreads();

  for (int s = 0; s < NSTEPS; ++s) {
    // ---- D1: LSTM cell, K = HH (token term folded via g_dsum) ----
    float acc[8][8];
    #pragma unroll
    for (int r = 0; r < 8; ++r)
      #pragma unroll
      for (int c = 0; c < 8; ++c) acc[r][c] = 0.0f;

    for (int ch = 0; ch < 16; ++ch) {
      const int k0 = ch * KT;
      __syncthreads();
      {
        const float* asrc = hc + (size_t)k0 * BB;
        #pragma unroll
        for (int i = 0; i < 4; ++i) {
          int fi = tid + i * NTHR;
          int kk = fi >> 4, c4 = (fi & 15) * 4;
          *(float4*)&As[kk][c4] = *(const float4*)&asrc[kk * BB + c4];
        }
      }
      {
        int row = tid >> 4, c4 = (tid & 15) * 4;
        int grow = (row >> 2) * HH + blk * 4 + (row & 3);
        float4 wv = *(const float4*)&dWhh[(size_t)grow * HH + k0 + c4];
        Wt[c4 + 0][row] = wv.x;
        Wt[c4 + 1][row] = wv.y;
        Wt[c4 + 2][row] = wv.z;
        Wt[c4 + 3][row] = wv.w;
      }
      __syncthreads();
      #pragma unroll
      for (int kk2 = 0; kk2 < 4; ++kk2) {
        const int kk = (kt << 2) | kk2;
        float4 a0 = *(const float4*)&As[kk][cg * 8];
        float4 a1 = *(const float4*)&As[kk][cg * 8 + 4];
        float4 w0 = *(const float4*)&Wt[kk][rg * 8];
        float4 w1 = *(const float4*)&Wt[kk][rg * 8 + 4];
        float av[8] = {a0.x, a0.y, a0.z, a0.w, a1.x, a1.y, a1.z, a1.w};
        float wv[8] = {w0.x, w0.y, w0.z, w0.w, w1.x, w1.y, w1.z, w1.w};
        #pragma unroll
        for (int r = 0; r < 8; ++r)
          #pragma unroll
          for (int c = 0; c < 8; ++c)
            acc[r][c] = fmaf(wv[r], av[c], acc[r][c]);
      }
    }
    __syncthreads();
    #pragma unroll
    for (int r = 0; r < 8; ++r) {
      float4 v0 = {acc[r][0], acc[r][1], acc[r][2], acc[r][3]};
      float4 v1 = {acc[r][4], acc[r][5], acc[r][6], acc[r][7]};
      *(float4*)&Gp[kt][rg * 8 + r][cg * 8]     = v0;
      *(float4*)&Gp[kt][rg * 8 + r][cg * 8 + 4] = v1;
    }
    __syncthreads();
    {
      float gsum[4];
      #pragma unroll
      for (int g = 0; g < 4; ++g) {
        const int rt = g * 4 + jj2;
        float ssum = 0.0f;
        #pragma unroll
        for (int q = 0; q < 16; ++q) ssum += Gp[q][rt][cb];
        gsum[g] = ssum;
      }
      float tk = ptok[cb];
      float pi = gsum[0] + dbih[j2]          + dbhh[j2]          + tk * g_dsum[j2];
      float pf = gsum[1] + dbih[HH + j2]     + dbhh[HH + j2]     + tk * g_dsum[HH + j2];
      float pg = gsum[2] + dbih[2 * HH + j2] + dbhh[2 * HH + j2] + tk * g_dsum[2 * HH + j2];
      float po = gsum[3] + dbih[3 * HH + j2] + dbhh[3 * HH + j2] + tk * g_dsum[3 * HH + j2];
      float co = g_cst[(size_t)j2 * BB + cb];
      float cn = sigf(pf) * co + sigf(pi) * tanhf(pg);
      float hv = sigf(po) * tanhf(cn);
      g_cst[(size_t)j2 * BB + cb] = cn;
      hn[(size_t)j2 * BB + cb] = hv;
    }
    grid_sync(cnt, ++sync_no * NBLK);
    { float* tmp = (float*)hc; hc = hn; hn = tmp; }   // hc = new h

    // ---- D2: logits = h @ fc_W^T + fc_b (blocks 0..127, 4 o-rows each) ----
    if (blk < 128) {
      float facc[4][8];
      #pragma unroll
      for (int r = 0; r < 4; ++r)
        #pragma unroll
        for (int c = 0; c < 8; ++c) facc[r][c] = 0.0f;

      for (int ch = 0; ch < 16; ++ch) {
        const int k0 = ch * KT;
        __syncthreads();
        {
          const float* asrc = hc + (size_t)k0 * BB;
          #pragma unroll
          for (int i = 0; i < 4; ++i) {
            int fi = tid + i * NTHR;
            int kk = fi >> 4, c4 = (fi & 15) * 4;
            *(float4*)&As[kk][c4] = *(const float4*)&asrc[kk * BB + c4];
          }
        }
        if (tid < 64) {
          int row = tid >> 4, c4 = (tid & 15) * 4;   // 4 fc rows
          float4 wv = *(const float4*)&fcW[(size_t)(blk * 4 + row) * HH + k0 + c4];
          Wt[c4 + 0][row] = wv.x;
          Wt[c4 + 1][row] = wv.y;
          Wt[c4 + 2][row] = wv.z;
          Wt[c4 + 3][row] = wv.w;
        }
        __syncthreads();
        #pragma unroll
        for (int kk2 = 0; kk2 < 2; ++kk2) {
          const int kk = (ktd << 1) | kk2;
          float4 a0 = *(const float4*)&As[kk][cgd * 8];
          float4 a1 = *(const float4*)&As[kk][cgd * 8 + 4];
          float4 w  = *(const float4*)&Wt[kk][0];
          float av[8] = {a0.x, a0.y, a0.z, a0.w, a1.x, a1.y, a1.z, a1.w};
          float wv[4] = {w.x, w.y, w.z, w.w};
          #pragma unroll
          for (int r = 0; r < 4; ++r)
            #pragma unroll
            for (int c = 0; c < 8; ++c)
              facc[r][c] = fmaf(wv[r], av[c], facc[r][c]);
        }
      }
      __syncthreads();
      #pragma unroll
      for (int r = 0; r < 4; ++r) {
        float4 v0 = {facc[r][0], facc[r][1], facc[r][2], facc[r][3]};
        float4 v1 = {facc[r][4], facc[r][5], facc[r][6], facc[r][7]};
        *(float4*)&Gpd[ktd * 276 + r * 68 + cgd * 8]     = v0;
        *(float4*)&Gpd[ktd * 276 + r * 68 + cgd * 8 + 4] = v1;
      }
      __syncthreads();
      {
        const int oo = tid >> 6, ob = tid & 63;
        float ssum = 0.0f;
        #pragma unroll
        for (int q = 0; q < 32; ++q) ssum += Gpd[q * 276 + oo * 68 + ob];
        const int o = blk * 4 + oo;
        g_logits[(size_t)o * BB + ob] = ssum + fcb[o];
      }
    }
    grid_sync(cnt, ++sync_no * NBLK);

    // ---- argmax (redundant per block; first-index tie-break) ----
    {
      const int q = tid >> 6, b = tid & 63;
      float bv = -3.402823466e38f; int bo = 0;
      for (int o = q * 128; o < q * 128 + 128; ++o) {
        float v = g_logits[(size_t)o * BB + b];
        if (v > bv) { bv = v; bo = o; }
      }
      avals[q][b] = bv; aidx[q][b] = bo;
    }
    __syncthreads();
    if (tid < BB) {
      float bv = avals[0][tid]; int bo = aidx[0][tid];
      #pragma unroll
      for (int q = 1; q < 4; ++q)
        if (avals[q][tid] > bv) { bv = avals[q][tid]; bo = aidx[q][tid]; }
      ptok[tid] = (float)bo;
      if (blk == 0) out[(size_t)tid * NSTEPS + s] = bo;   // int32 tokens
    }
    __syncthreads();
  }
}

extern "C" void kernel_launch(void* const* d_in, const int* in_sizes, int n_in,
                              void* d_out, int out_size, void* d_ws, size_t ws_size,
                              hipStream_t stream) {
  (void)in_sizes; (void)n_in; (void)out_size; (void)d_ws; (void)ws_size;
  const float* xin  = (const float*)d_in[0];
  const float* eWih = (const float*)d_in[1];
  const float* eWhh = (const float*)d_in[2];
  const float* ebih = (const float*)d_in[3];
  const float* ebhh = (const float*)d_in[4];
  const float* dWih = (const float*)d_in[5];
  const float* dWhh = (const float*)d_in[6];
  const float* dbih = (const float*)d_in[7];
  const float* dbhh = (const float*)d_in[8];
  const float* fcW  = (const float*)d_in[9];
  const float* fcb  = (const float*)d_in[10];
  int* out = (int*)d_out;

  reset_counter<<<1, 1, 0, stream>>>();
  seq2seq_kernel<<<NBLK, NTHR, 0, stream>>>(
      xin, eWih, eWhh, ebih, ebhh, dWih, dWhh, dbih, dbhh, fcW, fcb, out);
}

// Round 4
// 20051.997 us; speedup vs baseline: 1.4665x; 1.1221x over previous
//
#include <hip/hip_runtime.h>
#include <cstdint>
#include <cmath>

#define BB 64
#define TT 512
#define NI 256
#define HH 1024
#define NO 512
#define NSTEPS 100
#define KT 64
#define NBLK 256
#define NTHR 256

// ---- persistent device-global state (module-owned; NOT in d_ws) ----
__device__ unsigned g_cnt;
__device__ float g_hA[HH * BB];
__device__ float g_hB[HH * BB];
__device__ float g_cst[HH * BB];
__device__ float g_dsum[4 * HH];
__device__ float g_logits[NO * BB];
__device__ float g_xt[TT * NI * BB];   // x transposed to [t][k][b]

__device__ __forceinline__ float sigf(float x) { return 1.0f / (1.0f + expf(-x)); }

// Monotonic grid barrier (ockl grid-sync pattern).
__device__ __forceinline__ void grid_sync(unsigned* cnt, unsigned target) {
  __syncthreads();
  if (threadIdx.x == 0) {
    __builtin_amdgcn_fence(__ATOMIC_RELEASE, "agent");
    __hip_atomic_fetch_add(cnt, 1u, __ATOMIC_RELAXED, __HIP_MEMORY_SCOPE_AGENT);
    while (__hip_atomic_load(cnt, __ATOMIC_RELAXED, __HIP_MEMORY_SCOPE_AGENT) < target) {
      __builtin_amdgcn_s_sleep(2);
    }
    __builtin_amdgcn_fence(__ATOMIC_ACQUIRE, "agent");
  }
  __syncthreads();
}

__global__ void reset_counter() { g_cnt = 0u; }

// prefetch regs -> LDS (A tile + W tile); W comes pre-transposed from global
#define LOAD_A(asrc) \
  { ar0 = *(const float4*)&(asrc)[a_base]; \
    ar1 = *(const float4*)&(asrc)[a_base + 1024]; \
    ar2 = *(const float4*)&(asrc)[a_base + 2048]; \
    ar3 = *(const float4*)&(asrc)[a_base + 3072]; }

#define LOAD_W(wp, ld) \
  { wr.x = (wp)[0]; wr.y = (wp)[(size_t)(ld)]; \
    wr.z = (wp)[2 * (size_t)(ld)]; wr.w = (wp)[3 * (size_t)(ld)]; }

#define STORE_LDS(bufi) \
  { float* ab = &As[bufi][0][0]; \
    *(float4*)&ab[a_base]        = ar0; \
    *(float4*)&ab[a_base + 1024] = ar1; \
    *(float4*)&ab[a_base + 2048] = ar2; \
    *(float4*)&ab[a_base + 3072] = ar3; \
    *(float4*)&Wt[bufi][kkl][rq * 4] = wr; }

#define FMA_CHUNK(bufi) \
  _Pragma("unroll") \
  for (int kk2 = 0; kk2 < 4; ++kk2) { \
    const int kk = (kt << 2) | kk2; \
    float4 a0 = *(const float4*)&As[bufi][kk][cg * 8]; \
    float4 a1 = *(const float4*)&As[bufi][kk][cg * 8 + 4]; \
    float4 w0 = *(const float4*)&Wt[bufi][kk][rg * 8]; \
    float4 w1 = *(const float4*)&Wt[bufi][kk][rg * 8 + 4]; \
    float av[8] = {a0.x, a0.y, a0.z, a0.w, a1.x, a1.y, a1.z, a1.w}; \
    float wv[8] = {w0.x, w0.y, w0.z, w0.w, w1.x, w1.y, w1.z, w1.w}; \
    _Pragma("unroll") for (int r = 0; r < 8; ++r) \
      _Pragma("unroll") for (int c = 0; c < 8; ++c) \
        acc[r][c] = fmaf(wv[r], av[c], acc[r][c]); \
  }

__global__ void __launch_bounds__(NTHR, 1)
seq2seq_kernel(const float* __restrict__ xin,
               const float* __restrict__ eWih, const float* __restrict__ eWhh,
               const float* __restrict__ ebih, const float* __restrict__ ebhh,
               const float* __restrict__ dWih, const float* __restrict__ dWhh,
               const float* __restrict__ dbih, const float* __restrict__ dbhh,
               const float* __restrict__ fcW,  const float* __restrict__ fcb,
               int* __restrict__ out)
{
  __shared__ __align__(16) float As[2][KT][BB];     // 32 KB double-buffered A
  __shared__ __align__(16) float Wt[2][KT][20];     // 10 KB double-buffered W^T
  __shared__ __align__(16) float Gp[16][17][68];    // 74 KB K-split partials
  __shared__ float avals[4][BB];
  __shared__ int   aidx[4][BB];
  __shared__ float ptok[BB];

  const int tid = threadIdx.x;
  const int blk = blockIdx.x;
  unsigned sync_no = 0;
  unsigned* cnt = &g_cnt;

  // GEMM mapping: 16 K-subgroups x (2 row-groups x 8 batch-groups)
  const int kt = tid >> 4;            // 0..15
  const int cg = tid & 7;             // batch group (x8)
  const int rg = (tid >> 3) & 1;      // row group (x8)
  // combine-phase mapping
  const int jj2 = tid >> 6;           // 0..3
  const int cb  = tid & 63;
  const int j2  = blk * 4 + jj2;
  // W staging mapping: wave rq loads gate rq's 4 rows at k = kkl
  const int rq  = tid >> 6;           // 0..3 (gate)
  const int kkl = tid & 63;
  // A staging offset (same linear layout in source and LDS)
  const int a_base = (tid >> 4) * 64 + (tid & 15) * 4;
  float* const Gpd = &Gp[0][0][0];    // D2 alias: [32][276]

  // ---------------- init ----------------
  {
    int idx = blk * NTHR + tid;
    g_hA[idx]  = 0.0f;
    g_cst[idx] = 0.0f;
    int r = blk * 16 + (tid >> 4);
    int l16 = tid & 15;
    const float* wrp = dWih + (size_t)r * NO;
    float s = 0.0f;
    for (int k = l16; k < NO; k += 16) s += wrp[k];
    for (int off = 8; off; off >>= 1) s += __shfl_down(s, off, 16);
    if (l16 == 0) g_dsum[r] = s;
    for (int w = blk * NTHR + tid; w < TT * NI * BB; w += NBLK * NTHR) {
      int b = w & 63;
      int tk = w >> 6;
      int k = tk & (NI - 1);
      int t = tk >> 8;
      g_xt[w] = xin[((size_t)b * TT + t) * NI + k];
    }
  }
  // loop-invariant encoder biases
  const float be0 = ebih[j2]          + ebhh[j2];
  const float be1 = ebih[HH + j2]     + ebhh[HH + j2];
  const float be2 = ebih[2 * HH + j2] + ebhh[2 * HH + j2];
  const float be3 = ebih[3 * HH + j2] + ebhh[3 * HH + j2];
  grid_sync(cnt, ++sync_no * NBLK);

  const float* hc = g_hA;
  float* hn = g_hB;

  // ================ encoder: 512 steps ================
  for (int t = 0; t < TT; ++t) {
    float acc[8][8];
    #pragma unroll
    for (int r = 0; r < 8; ++r)
      #pragma unroll
      for (int c = 0; c < 8; ++c) acc[r][c] = 0.0f;

    float4 ar0, ar1, ar2, ar3, wr;
    // prologue: chunk 0 (x-part)
    {
      const float* ap = g_xt + (size_t)t * NI * BB;
      LOAD_A(ap);
      const float* wp = eWih + (size_t)(rq * HH + blk * 4) * NI + kkl;
      LOAD_W(wp, NI);
    }
    STORE_LDS(0);
    for (int ch = 0; ch < 20; ++ch) {
      const int buf = ch & 1;
      if (ch + 1 < 20) {
        const int c1 = ch + 1;
        const float* ap = (c1 < 4) ? (g_xt + ((size_t)t * NI + c1 * KT) * BB)
                                   : (hc + (size_t)(c1 * KT - NI) * BB);
        LOAD_A(ap);
        if (c1 < 4) {
          const float* wp = eWih + (size_t)(rq * HH + blk * 4) * NI + c1 * KT + kkl;
          LOAD_W(wp, NI);
        } else {
          const float* wp = eWhh + (size_t)(rq * HH + blk * 4) * HH + (c1 * KT - NI) + kkl;
          LOAD_W(wp, HH);
        }
      }
      __syncthreads();
      FMA_CHUNK(buf);
      if (ch + 1 < 20) STORE_LDS(buf ^ 1);
    }
    // K-split partials -> LDS
    __syncthreads();
    #pragma unroll
    for (int r = 0; r < 8; ++r) {
      float4 v0 = {acc[r][0], acc[r][1], acc[r][2], acc[r][3]};
      float4 v1 = {acc[r][4], acc[r][5], acc[r][6], acc[r][7]};
      *(float4*)&Gp[kt][rg * 8 + r][cg * 8]     = v0;
      *(float4*)&Gp[kt][rg * 8 + r][cg * 8 + 4] = v1;
    }
    __syncthreads();
    {
      float gsum[4];
      #pragma unroll
      for (int g = 0; g < 4; ++g) {
        const int rt = g * 4 + jj2;
        float s = 0.0f;
        #pragma unroll
        for (int q = 0; q < 16; ++q) s += Gp[q][rt][cb];
        gsum[g] = s;
      }
      float pi = gsum[0] + be0;
      float pf = gsum[1] + be1;
      float pg = gsum[2] + be2;
      float po = gsum[3] + be3;
      float co = g_cst[(size_t)j2 * BB + cb];
      float cn = sigf(pf) * co + sigf(pi) * tanhf(pg);
      float hv = sigf(po) * tanhf(cn);
      g_cst[(size_t)j2 * BB + cb] = cn;
      hn[(size_t)j2 * BB + cb] = hv;
    }
    grid_sync(cnt, ++sync_no * NBLK);
    float* tmp = (float*)hc; hc = hn; hn = tmp;
  }

  // ================ decoder: 100 steps ================
  if (tid < BB) ptok[tid] = 0.0f;
  __syncthreads();
  // loop-invariant decoder biases + dec_Wih rowsums
  const float bd0 = dbih[j2]          + dbhh[j2];
  const float bd1 = dbih[HH + j2]     + dbhh[HH + j2];
  const float bd2 = dbih[2 * HH + j2] + dbhh[2 * HH + j2];
  const float bd3 = dbih[3 * HH + j2] + dbhh[3 * HH + j2];
  const float ds0 = g_dsum[j2];
  const float ds1 = g_dsum[HH + j2];
  const float ds2 = g_dsum[2 * HH + j2];
  const float ds3 = g_dsum[3 * HH + j2];

  for (int s = 0; s < NSTEPS; ++s) {
    // ---- D1: LSTM cell, K = HH ----
    float acc[8][8];
    #pragma unroll
    for (int r = 0; r < 8; ++r)
      #pragma unroll
      for (int c = 0; c < 8; ++c) acc[r][c] = 0.0f;

    float4 ar0, ar1, ar2, ar3, wr;
    {
      LOAD_A(hc);
      const float* wp = dWhh + (size_t)(rq * HH + blk * 4) * HH + kkl;
      LOAD_W(wp, HH);
    }
    STORE_LDS(0);
    for (int ch = 0; ch < 16; ++ch) {
      const int buf = ch & 1;
      if (ch + 1 < 16) {
        const float* ap = hc + (size_t)(ch + 1) * KT * BB;
        LOAD_A(ap);
        const float* wp = dWhh + (size_t)(rq * HH + blk * 4) * HH + (ch + 1) * KT + kkl;
        LOAD_W(wp, HH);
      }
      __syncthreads();
      FMA_CHUNK(buf);
      if (ch + 1 < 16) STORE_LDS(buf ^ 1);
    }
    __syncthreads();
    #pragma unroll
    for (int r = 0; r < 8; ++r) {
      float4 v0 = {acc[r][0], acc[r][1], acc[r][2], acc[r][3]};
      float4 v1 = {acc[r][4], acc[r][5], acc[r][6], acc[r][7]};
      *(float4*)&Gp[kt][rg * 8 + r][cg * 8]     = v0;
      *(float4*)&Gp[kt][rg * 8 + r][cg * 8 + 4] = v1;
    }
    __syncthreads();
    {
      float gsum[4];
      #pragma unroll
      for (int g = 0; g < 4; ++g) {
        const int rt = g * 4 + jj2;
        float ssum = 0.0f;
        #pragma unroll
        for (int q = 0; q < 16; ++q) ssum += Gp[q][rt][cb];
        gsum[g] = ssum;
      }
      float tk = ptok[cb];
      float pi = gsum[0] + bd0 + tk * ds0;
      float pf = gsum[1] + bd1 + tk * ds1;
      float pg = gsum[2] + bd2 + tk * ds2;
      float po = gsum[3] + bd3 + tk * ds3;
      float co = g_cst[(size_t)j2 * BB + cb];
      float cn = sigf(pf) * co + sigf(pi) * tanhf(pg);
      float hv = sigf(po) * tanhf(cn);
      g_cst[(size_t)j2 * BB + cb] = cn;
      hn[(size_t)j2 * BB + cb] = hv;
    }
    grid_sync(cnt, ++sync_no * NBLK);
    { float* tmp = (float*)hc; hc = hn; hn = tmp; }   // hc = new h

    // ---- D2: logits = h @ fc_W^T + fc_b (blocks 0..127, 4 o-rows each) ----
    if (blk < 128) {
      float facc[4][8];
      #pragma unroll
      for (int r = 0; r < 4; ++r)
        #pragma unroll
        for (int c = 0; c < 8; ++c) facc[r][c] = 0.0f;

      const int ktd2 = kt * 2 + rg;    // 0..31 K-split
      float4 ar0, ar1, ar2, ar3;
      float fw;
      {
        LOAD_A(hc);
        fw = fcW[(size_t)(blk * 4 + rq) * HH + kkl];
      }
      { float* ab = &As[0][0][0];
        *(float4*)&ab[a_base]        = ar0;
        *(float4*)&ab[a_base + 1024] = ar1;
        *(float4*)&ab[a_base + 2048] = ar2;
        *(float4*)&ab[a_base + 3072] = ar3;
        Wt[0][kkl][rq] = fw; }
      for (int ch = 0; ch < 16; ++ch) {
        const int buf = ch & 1;
        if (ch + 1 < 16) {
          const float* ap = hc + (size_t)(ch + 1) * KT * BB;
          LOAD_A(ap);
          fw = fcW[(size_t)(blk * 4 + rq) * HH + (ch + 1) * KT + kkl];
        }
        __syncthreads();
        #pragma unroll
        for (int i = 0; i < 2; ++i) {
          const int kk = ktd2 * 2 + i;
          float4 a0 = *(const float4*)&As[buf][kk][cg * 8];
          float4 a1 = *(const float4*)&As[buf][kk][cg * 8 + 4];
          float4 w  = *(const float4*)&Wt[buf][kk][0];
          float av[8] = {a0.x, a0.y, a0.z, a0.w, a1.x, a1.y, a1.z, a1.w};
          float wv[4] = {w.x, w.y, w.z, w.w};
          #pragma unroll
          for (int r = 0; r < 4; ++r)
            #pragma unroll
            for (int c = 0; c < 8; ++c)
              facc[r][c] = fmaf(wv[r], av[c], facc[r][c]);
        }
        if (ch + 1 < 16) {
          float* ab = &As[buf ^ 1][0][0];
          *(float4*)&ab[a_base]        = ar0;
          *(float4*)&ab[a_base + 1024] = ar1;
          *(float4*)&ab[a_base + 2048] = ar2;
          *(float4*)&ab[a_base + 3072] = ar3;
          Wt[buf ^ 1][kkl][rq] = fw;
        }
      }
      __syncthreads();
      #pragma unroll
      for (int r = 0; r < 4; ++r) {
        float4 v0 = {facc[r][0], facc[r][1], facc[r][2], facc[r][3]};
        float4 v1 = {facc[r][4], facc[r][5], facc[r][6], facc[r][7]};
        *(float4*)&Gpd[ktd2 * 276 + r * 68 + cg * 8]     = v0;
        *(float4*)&Gpd[ktd2 * 276 + r * 68 + cg * 8 + 4] = v1;
      }
      __syncthreads();
      {
        const int oo = tid >> 6, ob = tid & 63;
        float ssum = 0.0f;
        #pragma unroll
        for (int q = 0; q < 32; ++q) ssum += Gpd[q * 276 + oo * 68 + ob];
        const int o = blk * 4 + oo;
        g_logits[(size_t)o * BB + ob] = ssum + fcb[o];
      }
    }
    grid_sync(cnt, ++sync_no * NBLK);

    // ---- argmax (redundant per block; first-index tie-break) ----
    {
      const int q = tid >> 6, b = tid & 63;
      float bv = -3.402823466e38f; int bo = 0;
      for (int o = q * 128; o < q * 128 + 128; ++o) {
        float v = g_logits[(size_t)o * BB + b];
        if (v > bv) { bv = v; bo = o; }
      }
      avals[q][b] = bv; aidx[q][b] = bo;
    }
    __syncthreads();
    if (tid < BB) {
      float bv = avals[0][tid]; int bo = aidx[0][tid];
      #pragma unroll
      for (int q = 1; q < 4; ++q)
        if (avals[q][tid] > bv) { bv = avals[q][tid]; bo = aidx[q][tid]; }
      ptok[tid] = (float)bo;
      if (blk == 0) out[(size_t)tid * NSTEPS + s] = bo;   // int32 tokens
    }
    __syncthreads();
  }
}

extern "C" void kernel_launch(void* const* d_in, const int* in_sizes, int n_in,
                              void* d_out, int out_size, void* d_ws, size_t ws_size,
                              hipStream_t stream) {
  (void)in_sizes; (void)n_in; (void)out_size; (void)d_ws; (void)ws_size;
  const float* xin  = (const float*)d_in[0];
  const float* eWih = (const float*)d_in[1];
  const float* eWhh = (const float*)d_in[2];
  const float* ebih = (const float*)d_in[3];
  const float* ebhh = (const float*)d_in[4];
  const float* dWih = (const float*)d_in[5];
  const float* dWhh = (const float*)d_in[6];
  const float* dbih = (const float*)d_in[7];
  const float* dbhh = (const float*)d_in[8];
  const float* fcW  = (const float*)d_in[9];
  const float* fcb  = (const float*)d_in[10];
  int* out = (int*)d_out;

  reset_counter<<<1, 1, 0, stream>>>();
  seq2seq_kernel<<<NBLK, NTHR, 0, stream>>>(
      xin, eWih, eWhh, ebih, ebhh, dWih, dWhh, dbih, dbhh, fcW, fcb, out);
}

// Round 5
// 17221.556 us; speedup vs baseline: 1.7076x; 1.1644x over previous
//
#include <hip/hip_runtime.h>
#include <cstdint>
#include <cmath>

#define BB 64
#define TT 512
#define NI 256
#define HH 1024
#define NO 512
#define NSTEPS 100
#define KT 64
#define NBLK 256
#define NTHR 256
#define NCTR 16

// ---- persistent device-global state (module-owned; NOT in d_ws) ----
__device__ unsigned g_arr[(NCTR + 1) * 32];  // 16 arrival lines (128B apart) + flag line
__device__ float g_hA[HH * BB];
__device__ float g_hB[HH * BB];
__device__ float g_cst[HH * BB];
__device__ float g_dsum[4 * HH];
__device__ float g_logits[NO * BB];
__device__ float g_xt[TT * NI * BB];   // x transposed to [t][k][b]

__device__ __forceinline__ float sigf(float x) { return 1.0f / (1.0f + expf(-x)); }

// Distributed grid barrier: 16 arrival counters (parallel RMW chains),
// master (blk 0) aggregates and publishes monotonic epoch flag.
__device__ __forceinline__ void grid_sync(int blk, unsigned n) {
  __syncthreads();   // drains each wave's vmcnt (compiler emits waitcnt before s_barrier)
  if (threadIdx.x == 0) {
    __builtin_amdgcn_fence(__ATOMIC_RELEASE, "agent");
    __hip_atomic_fetch_add(&g_arr[(blk & (NCTR - 1)) * 32], 1u,
                           __ATOMIC_RELAXED, __HIP_MEMORY_SCOPE_AGENT);
    if (blk == 0) {
      for (;;) {
        unsigned tot = 0;
        #pragma unroll
        for (int i = 0; i < NCTR; ++i)
          tot += __hip_atomic_load(&g_arr[i * 32], __ATOMIC_RELAXED, __HIP_MEMORY_SCOPE_AGENT);
        if (tot >= n * NBLK) break;
        __builtin_amdgcn_s_sleep(1);
      }
      __hip_atomic_store(&g_arr[NCTR * 32], n, __ATOMIC_RELAXED, __HIP_MEMORY_SCOPE_AGENT);
    } else {
      while (__hip_atomic_load(&g_arr[NCTR * 32], __ATOMIC_RELAXED, __HIP_MEMORY_SCOPE_AGENT) < n)
        __builtin_amdgcn_s_sleep(2);
    }
    __builtin_amdgcn_fence(__ATOMIC_ACQUIRE, "agent");
  }
  __syncthreads();
}

__global__ void reset_counter() {
  if (threadIdx.x <= NCTR) g_arr[threadIdx.x * 32] = 0u;
}

#define LOAD_A(asrc) \
  { ar0 = *(const float4*)&(asrc)[a_base]; \
    ar1 = *(const float4*)&(asrc)[a_base + 1024]; \
    ar2 = *(const float4*)&(asrc)[a_base + 2048]; \
    ar3 = *(const float4*)&(asrc)[a_base + 3072]; }

#define LOAD_W(wp, ld) \
  { wr.x = (wp)[0]; wr.y = (wp)[(size_t)(ld)]; \
    wr.z = (wp)[2 * (size_t)(ld)]; wr.w = (wp)[3 * (size_t)(ld)]; }

#define STORE_LDS(bufi) \
  { float* ab = &As[bufi][0][0]; \
    *(float4*)&ab[a_base]        = ar0; \
    *(float4*)&ab[a_base + 1024] = ar1; \
    *(float4*)&ab[a_base + 2048] = ar2; \
    *(float4*)&ab[a_base + 3072] = ar3; \
    *(float4*)&Wt[bufi][kkl][rq * 4] = wr; }

#define FMA_CHUNK(bufi) \
  _Pragma("unroll") \
  for (int kk2 = 0; kk2 < 4; ++kk2) { \
    const int kk = (kt << 2) | kk2; \
    float4 a0 = *(const float4*)&As[bufi][kk][cg * 8]; \
    float4 a1 = *(const float4*)&As[bufi][kk][cg * 8 + 4]; \
    float4 w0 = *(const float4*)&Wt[bufi][kk][rg * 8]; \
    float4 w1 = *(const float4*)&Wt[bufi][kk][rg * 8 + 4]; \
    float av[8] = {a0.x, a0.y, a0.z, a0.w, a1.x, a1.y, a1.z, a1.w}; \
    float wv[8] = {w0.x, w0.y, w0.z, w0.w, w1.x, w1.y, w1.z, w1.w}; \
    _Pragma("unroll") for (int r = 0; r < 8; ++r) \
      _Pragma("unroll") for (int c = 0; c < 8; ++c) \
        acc[r][c] = fmaf(wv[r], av[c], acc[r][c]); \
  }

__global__ void __launch_bounds__(NTHR, 1)
seq2seq_kernel(const float* __restrict__ xin,
               const float* __restrict__ eWih, const float* __restrict__ eWhh,
               const float* __restrict__ ebih, const float* __restrict__ ebhh,
               const float* __restrict__ dWih, const float* __restrict__ dWhh,
               const float* __restrict__ dbih, const float* __restrict__ dbhh,
               const float* __restrict__ fcW,  const float* __restrict__ fcb,
               int* __restrict__ out)
{
  __shared__ __align__(16) float As[2][KT][BB];     // 32 KB double-buffered A
  __shared__ __align__(16) float Wt[2][KT][20];     // 10 KB double-buffered W^T
  __shared__ __align__(16) float Gp[16][17][68];    // 74 KB K-split partials
  __shared__ float avals[4][BB];
  __shared__ int   aidx[4][BB];
  __shared__ float ptok[BB];

  const int tid = threadIdx.x;
  const int blk = blockIdx.x;
  unsigned sync_no = 0;

  const int kt = tid >> 4;            // 0..15 K-subgroup
  const int cg = tid & 7;             // batch group (x8)
  const int rg = (tid >> 3) & 1;      // row group (x8)
  const int jj2 = tid >> 6;           // 0..3 (wave)
  const int cb  = tid & 63;
  const int j2  = blk * 4 + jj2;
  const int rq  = tid >> 6;           // W staging: wave rq loads gate rq's 4 rows
  const int kkl = tid & 63;
  const int a_base = (tid >> 4) * 64 + (tid & 15) * 4;
  float* const Gpd = &Gp[0][0][0];    // D2 alias: [32][276]

  // ---------------- init ----------------
  {
    int idx = blk * NTHR + tid;
    g_hA[idx]  = 0.0f;
    g_cst[idx] = 0.0f;
    int r = blk * 16 + (tid >> 4);
    int l16 = tid & 15;
    const float* wrp = dWih + (size_t)r * NO;
    float s = 0.0f;
    for (int k = l16; k < NO; k += 16) s += wrp[k];
    for (int off = 8; off; off >>= 1) s += __shfl_down(s, off, 16);
    if (l16 == 0) g_dsum[r] = s;
    for (int w = blk * NTHR + tid; w < TT * NI * BB; w += NBLK * NTHR) {
      int b = w & 63;
      int tk = w >> 6;
      int k = tk & (NI - 1);
      int t = tk >> 8;
      g_xt[w] = xin[((size_t)b * TT + t) * NI + k];
    }
  }
  const float be0 = ebih[j2]          + ebhh[j2];
  const float be1 = ebih[HH + j2]     + ebhh[HH + j2];
  const float be2 = ebih[2 * HH + j2] + ebhh[2 * HH + j2];
  const float be3 = ebih[3 * HH + j2] + ebhh[3 * HH + j2];
  grid_sync(blk, ++sync_no);

  const float* hc = g_hA;
  float* hn = g_hB;

  float4 ar0, ar1, ar2, ar3, wr;
  // prologue loads for t=0 chunk 0 (x + eWih; g_xt valid after init sync)
  {
    LOAD_A(g_xt);
    const float* wp = eWih + (size_t)(rq * HH + blk * 4) * NI + kkl;
    LOAD_W(wp, NI);
  }

  // ================ encoder: 512 steps ================
  for (int t = 0; t < TT; ++t) {
    float acc[8][8];
    #pragma unroll
    for (int r = 0; r < 8; ++r)
      #pragma unroll
      for (int c = 0; c < 8; ++c) acc[r][c] = 0.0f;

    STORE_LDS(0);                      // regs hoisted across the barrier
    for (int ch = 0; ch < 20; ++ch) {
      const int buf = ch & 1;
      if (ch + 1 < 20) {
        const int c1 = ch + 1;
        const float* ap = (c1 < 4) ? (g_xt + ((size_t)t * NI + c1 * KT) * BB)
                                   : (hc + (size_t)(c1 * KT - NI) * BB);
        LOAD_A(ap);
        if (c1 < 4) {
          const float* wp = eWih + (size_t)(rq * HH + blk * 4) * NI + c1 * KT + kkl;
          LOAD_W(wp, NI);
        } else {
          const float* wp = eWhh + (size_t)(rq * HH + blk * 4) * HH + (c1 * KT - NI) + kkl;
          LOAD_W(wp, HH);
        }
      }
      __syncthreads();
      FMA_CHUNK(buf);
      if (ch + 1 < 20) STORE_LDS(buf ^ 1);
    }
    __syncthreads();
    #pragma unroll
    for (int r = 0; r < 8; ++r) {
      float4 v0 = {acc[r][0], acc[r][1], acc[r][2], acc[r][3]};
      float4 v1 = {acc[r][4], acc[r][5], acc[r][6], acc[r][7]};
      *(float4*)&Gp[kt][rg * 8 + r][cg * 8]     = v0;
      *(float4*)&Gp[kt][rg * 8 + r][cg * 8 + 4] = v1;
    }
    __syncthreads();
    {
      float gsum[4];
      #pragma unroll
      for (int g = 0; g < 4; ++g) {
        const int rt = g * 4 + jj2;
        float s = 0.0f;
        #pragma unroll
        for (int q = 0; q < 16; ++q) s += Gp[q][rt][cb];
        gsum[g] = s;
      }
      float pi = gsum[0] + be0;
      float pf = gsum[1] + be1;
      float pg = gsum[2] + be2;
      float po = gsum[3] + be3;
      float co = g_cst[(size_t)j2 * BB + cb];
      float cn = sigf(pf) * co + sigf(pi) * tanhf(pg);
      float hv = sigf(po) * tanhf(cn);
      g_cst[(size_t)j2 * BB + cb] = cn;
      hn[(size_t)j2 * BB + cb] = hv;
    }
    // tail hoist: next step's chunk 0 (x static, eWih static) — in flight during barrier
    {
      const int tn = (t + 1 < TT) ? t + 1 : t;
      LOAD_A(g_xt + (size_t)tn * NI * BB);
      const float* wp = eWih + (size_t)(rq * HH + blk * 4) * NI + kkl;
      LOAD_W(wp, NI);
    }
    grid_sync(blk, ++sync_no);
    float* tmp = (float*)hc; hc = hn; hn = tmp;
  }

  // ================ decoder: 100 steps ================
  if (tid < BB) ptok[tid] = 0.0f;
  const float bd0 = dbih[j2]          + dbhh[j2];
  const float bd1 = dbih[HH + j2]     + dbhh[HH + j2];
  const float bd2 = dbih[2 * HH + j2] + dbhh[2 * HH + j2];
  const float bd3 = dbih[3 * HH + j2] + dbhh[3 * HH + j2];
  const float ds0 = g_dsum[j2];
  const float ds1 = g_dsum[HH + j2];
  const float ds2 = g_dsum[2 * HH + j2];
  const float ds3 = g_dsum[3 * HH + j2];
  // D1 s=0 chunk-0 prologue (hc = final encoder h, already synced)
  {
    LOAD_A(hc);
    const float* wp = dWhh + (size_t)(rq * HH + blk * 4) * HH + kkl;
    LOAD_W(wp, HH);
  }
  __syncthreads();   // ptok init visible

  for (int s = 0; s < NSTEPS; ++s) {
    // ---- D1: LSTM cell, K = HH ----
    float acc[8][8];
    #pragma unroll
    for (int r = 0; r < 8; ++r)
      #pragma unroll
      for (int c = 0; c < 8; ++c) acc[r][c] = 0.0f;

    STORE_LDS(0);
    for (int ch = 0; ch < 16; ++ch) {
      const int buf = ch & 1;
      if (ch + 1 < 16) {
        LOAD_A(hc + (size_t)(ch + 1) * KT * BB);
        const float* wp = dWhh + (size_t)(rq * HH + blk * 4) * HH + (ch + 1) * KT + kkl;
        LOAD_W(wp, HH);
      }
      __syncthreads();
      FMA_CHUNK(buf);
      if (ch + 1 < 16) STORE_LDS(buf ^ 1);
    }
    __syncthreads();
    #pragma unroll
    for (int r = 0; r < 8; ++r) {
      float4 v0 = {acc[r][0], acc[r][1], acc[r][2], acc[r][3]};
      float4 v1 = {acc[r][4], acc[r][5], acc[r][6], acc[r][7]};
      *(float4*)&Gp[kt][rg * 8 + r][cg * 8]     = v0;
      *(float4*)&Gp[kt][rg * 8 + r][cg * 8 + 4] = v1;
    }
    __syncthreads();
    {
      float gsum[4];
      #pragma unroll
      for (int g = 0; g < 4; ++g) {
        const int rt = g * 4 + jj2;
        float ssum = 0.0f;
        #pragma unroll
        for (int q = 0; q < 16; ++q) ssum += Gp[q][rt][cb];
        gsum[g] = ssum;
      }
      float tk = ptok[cb];
      float pi = gsum[0] + bd0 + tk * ds0;
      float pf = gsum[1] + bd1 + tk * ds1;
      float pg = gsum[2] + bd2 + tk * ds2;
      float po = gsum[3] + bd3 + tk * ds3;
      float co = g_cst[(size_t)j2 * BB + cb];
      float cn = sigf(pf) * co + sigf(pi) * tanhf(pg);
      float hv = sigf(po) * tanhf(cn);
      g_cst[(size_t)j2 * BB + cb] = cn;
      hn[(size_t)j2 * BB + cb] = hv;
    }
    float fw0 = 0.0f;
    if (blk < 128) fw0 = fcW[(size_t)(blk * 4 + rq) * HH + kkl];   // hoisted (static)
    grid_sync(blk, ++sync_no);
    { float* tmp = (float*)hc; hc = hn; hn = tmp; }   // hc = new h

    // ---- D2: logits (blocks 0..127, 4 o-rows each) ----
    if (blk < 128) {
      float facc[4][8];
      #pragma unroll
      for (int r = 0; r < 4; ++r)
        #pragma unroll
        for (int c = 0; c < 8; ++c) facc[r][c] = 0.0f;

      const int ktd2 = kt * 2 + rg;    // 0..31 K-split
      float fw;
      LOAD_A(hc);                       // fresh h — must be after sync
      { float* ab = &As[0][0][0];
        *(float4*)&ab[a_base]        = ar0;
        *(float4*)&ab[a_base + 1024] = ar1;
        *(float4*)&ab[a_base + 2048] = ar2;
        *(float4*)&ab[a_base + 3072] = ar3;
        Wt[0][kkl][rq] = fw0; }
      for (int ch = 0; ch < 16; ++ch) {
        const int buf = ch & 1;
        if (ch + 1 < 16) {
          LOAD_A(hc + (size_t)(ch + 1) * KT * BB);
          fw = fcW[(size_t)(blk * 4 + rq) * HH + (ch + 1) * KT + kkl];
        }
        __syncthreads();
        #pragma unroll
        for (int i = 0; i < 2; ++i) {
          const int kk = ktd2 * 2 + i;
          float4 a0 = *(const float4*)&As[buf][kk][cg * 8];
          float4 a1 = *(const float4*)&As[buf][kk][cg * 8 + 4];
          float4 w  = *(const float4*)&Wt[buf][kk][0];
          float av[8] = {a0.x, a0.y, a0.z, a0.w, a1.x, a1.y, a1.z, a1.w};
          float wv[4] = {w.x, w.y, w.z, w.w};
          #pragma unroll
          for (int r = 0; r < 4; ++r)
            #pragma unroll
            for (int c = 0; c < 8; ++c)
              facc[r][c] = fmaf(wv[r], av[c], facc[r][c]);
        }
        if (ch + 1 < 16) {
          float* ab = &As[buf ^ 1][0][0];
          *(float4*)&ab[a_base]        = ar0;
          *(float4*)&ab[a_base + 1024] = ar1;
          *(float4*)&ab[a_base + 2048] = ar2;
          *(float4*)&ab[a_base + 3072] = ar3;
          Wt[buf ^ 1][kkl][rq] = fw;
        }
      }
      __syncthreads();
      #pragma unroll
      for (int r = 0; r < 4; ++r) {
        float4 v0 = {facc[r][0], facc[r][1], facc[r][2], facc[r][3]};
        float4 v1 = {facc[r][4], facc[r][5], facc[r][6], facc[r][7]};
        *(float4*)&Gpd[ktd2 * 276 + r * 68 + cg * 8]     = v0;
        *(float4*)&Gpd[ktd2 * 276 + r * 68 + cg * 8 + 4] = v1;
      }
      __syncthreads();
      {
        const int oo = tid >> 6, ob = tid & 63;
        float ssum = 0.0f;
        #pragma unroll
        for (int q = 0; q < 32; ++q) ssum += Gpd[q * 276 + oo * 68 + ob];
        const int o = blk * 4 + oo;
        g_logits[(size_t)o * BB + ob] = ssum + fcb[o];
      }
    }
    // tail hoist: next D1 chunk 0 (hc unchanged during D2/argmax — one-sync-old, visible)
    {
      LOAD_A(hc);
      const float* wp = dWhh + (size_t)(rq * HH + blk * 4) * HH + kkl;
      LOAD_W(wp, HH);
    }
    grid_sync(blk, ++sync_no);

    // ---- argmax (redundant per block; first-index tie-break) ----
    {
      const int q = tid >> 6, b = tid & 63;
      float bv = -3.402823466e38f; int bo = 0;
      for (int o = q * 128; o < q * 128 + 128; ++o) {
        float v = g_logits[(size_t)o * BB + b];
        if (v > bv) { bv = v; bo = o; }
      }
      avals[q][b] = bv; aidx[q][b] = bo;
    }
    __syncthreads();
    if (tid < BB) {
      float bv = avals[0][tid]; int bo = aidx[0][tid];
      #pragma unroll
      for (int q = 1; q < 4; ++q)
        if (avals[q][tid] > bv) { bv = avals[q][tid]; bo = aidx[q][tid]; }
      ptok[tid] = (float)bo;
      if (blk == 0) out[(size_t)tid * NSTEPS + s] = bo;   // int32 tokens
    }
    __syncthreads();
  }
}

extern "C" void kernel_launch(void* const* d_in, const int* in_sizes, int n_in,
                              void* d_out, int out_size, void* d_ws, size_t ws_size,
                              hipStream_t stream) {
  (void)in_sizes; (void)n_in; (void)out_size; (void)d_ws; (void)ws_size;
  const float* xin  = (const float*)d_in[0];
  const float* eWih = (const float*)d_in[1];
  const float* eWhh = (const float*)d_in[2];
  const float* ebih = (const float*)d_in[3];
  const float* ebhh = (const float*)d_in[4];
  const float* dWih = (const float*)d_in[5];
  const float* dWhh = (const float*)d_in[6];
  const float* dbih = (const float*)d_in[7];
  const float* dbhh = (const float*)d_in[8];
  const float* fcW  = (const float*)d_in[9];
  const float* fcb  = (const float*)d_in[10];
  int* out = (int*)d_out;

  reset_counter<<<1, 32, 0, stream>>>();
  seq2seq_kernel<<<NBLK, NTHR, 0, stream>>>(
      xin, eWih, eWhh, ebih, ebhh, dWih, dWhh, dbih, dbhh, fcW, fcb, out);
}

// Round 6
// 16237.181 us; speedup vs baseline: 1.8111x; 1.0606x over previous
//
#include <hip/hip_runtime.h>
#include <cstdint>
#include <cmath>

#define BB 64
#define TT 512
#define NI 256
#define HH 1024
#define NO 512
#define NSTEPS 100
#define KT 64
#define NBLK 256
#define NTHR 512
#define NCTR 64

// ---- persistent device-global state (module-owned; NOT in d_ws) ----
__device__ unsigned g_arr[(NCTR + 1) * 32];  // 64 arrival lines (128B apart) + flag line
__device__ float g_hA[HH * BB];
__device__ float g_hB[HH * BB];
__device__ float g_cst[HH * BB];
__device__ float g_dsum[4 * HH];
__device__ float g_logits[NO * BB];
__device__ float g_xt[TT * NI * BB];   // x transposed to [t][k][b]

__device__ __forceinline__ float sigf(float x) { return 1.0f / (1.0f + expf(-x)); }

__device__ __forceinline__ void bar_arrive(int blk) {
  __syncthreads();   // all waves' stores drained (vmcnt before s_barrier)
  if (threadIdx.x == 0) {
    __builtin_amdgcn_fence(__ATOMIC_RELEASE, "agent");
    __hip_atomic_fetch_add(&g_arr[(blk & (NCTR - 1)) * 32], 1u,
                           __ATOMIC_RELAXED, __HIP_MEMORY_SCOPE_AGENT);
  }
}

__device__ __forceinline__ void bar_wait(int blk, unsigned n) {
  if (threadIdx.x == 0) {
    if (blk == 0) {
      for (;;) {
        unsigned tot = 0;
        #pragma unroll
        for (int i = 0; i < NCTR; ++i)
          tot += __hip_atomic_load(&g_arr[i * 32], __ATOMIC_RELAXED, __HIP_MEMORY_SCOPE_AGENT);
        if (tot >= n * NBLK) break;
        __builtin_amdgcn_s_sleep(1);
      }
      __hip_atomic_store(&g_arr[NCTR * 32], n, __ATOMIC_RELAXED, __HIP_MEMORY_SCOPE_AGENT);
    } else {
      while (__hip_atomic_load(&g_arr[NCTR * 32], __ATOMIC_RELAXED, __HIP_MEMORY_SCOPE_AGENT) < n)
        __builtin_amdgcn_s_sleep(2);
    }
    __builtin_amdgcn_fence(__ATOMIC_ACQUIRE, "agent");
  }
  __syncthreads();
}

__global__ void reset_counter() {
  if (threadIdx.x <= NCTR) g_arr[threadIdx.x * 32] = 0u;
}

#define LOAD_A(asrc) \
  { ar0 = *(const float4*)&(asrc)[tid * 4]; \
    ar1 = *(const float4*)&(asrc)[tid * 4 + 2048]; }

#define LOAD_W2(wsrc, ld, k) \
  { const float* wp = (wsrc) + (size_t)grow0 * (ld) + (k) + kkl; \
    wr0 = wp[0]; wr1 = wp[(ld)]; }

#define STORE_LDS(bufi) \
  { float* ab = &As[bufi][0][0]; \
    *(float4*)&ab[tid * 4]        = ar0; \
    *(float4*)&ab[tid * 4 + 2048] = ar1; \
    float2 w2; w2.x = wr0; w2.y = wr1; \
    *(float2*)&Wt[bufi][kkl][r0] = w2; }

#define FMA_CHUNK(bufi) \
  _Pragma("unroll") \
  for (int kk2 = 0; kk2 < 2; ++kk2) { \
    const int kk = kt2 * 2 + kk2; \
    float4 a0 = *(const float4*)&As[bufi][kk][cg * 8]; \
    float4 a1 = *(const float4*)&As[bufi][kk][cg * 8 + 4]; \
    float4 w0 = *(const float4*)&Wt[bufi][kk][rg * 8]; \
    float4 w1 = *(const float4*)&Wt[bufi][kk][rg * 8 + 4]; \
    float av[8] = {a0.x, a0.y, a0.z, a0.w, a1.x, a1.y, a1.z, a1.w}; \
    float wv[8] = {w0.x, w0.y, w0.z, w0.w, w1.x, w1.y, w1.z, w1.w}; \
    _Pragma("unroll") for (int r = 0; r < 8; ++r) \
      _Pragma("unroll") for (int c = 0; c < 8; ++c) \
        acc[r][c] = fmaf(wv[r], av[c], acc[r][c]); \
  }

__global__ void __launch_bounds__(NTHR, 1)
seq2seq_kernel(const float* __restrict__ xin,
               const float* __restrict__ eWih, const float* __restrict__ eWhh,
               const float* __restrict__ ebih, const float* __restrict__ ebhh,
               const float* __restrict__ dWih, const float* __restrict__ dWhh,
               const float* __restrict__ dbih, const float* __restrict__ dbhh,
               const float* __restrict__ fcW,  const float* __restrict__ fcb,
               int* __restrict__ out)
{
  __shared__ __align__(16) float As[2][KT][BB];     // 32 KB double-buffered A
  __shared__ __align__(16) float Wt[2][KT][20];     // 10 KB double-buffered W^T
  __shared__ __align__(16) float Gp[16][17][68];    // 74 KB K-split partials
  __shared__ float avals[8][BB];
  __shared__ int   aidx[8][BB];
  __shared__ float ptok[BB];

  const int tid = threadIdx.x;
  const int blk = blockIdx.x;
  unsigned sync_no = 0;

  // main-GEMM mapping: wave wv(0..7), lane ln; K-split 32 = 16 groups x 2 halves
  const int wv  = tid >> 6;
  const int ln  = tid & 63;
  const int hi  = ln >> 5;              // lane half (merged via shfl_xor 32)
  const int l5  = ln & 31;
  const int ks16 = (wv << 1) | (l5 >> 4);          // 0..15 LDS K-group
  const int kt2  = ks16 * 2 + hi;                  // 0..31 reg K-group
  const int rg  = (l5 >> 3) & 1;        // row group (x8)
  const int cg  = l5 & 7;               // batch group (x8)
  // update mapping (tid<256): jj2 = tid>>6 (0..3), cb = tid&63
  const int jj2 = (tid >> 6) & 3;
  const int cb  = tid & 63;
  const int j2  = blk * 4 + jj2;        // safe for all tids
  // W staging: wave wv loads rows r0, r0+1 (consecutive, same gate)
  const int r0  = wv * 2;
  const int kkl = ln;
  const int grow0 = ((r0 >> 2) * HH + blk * 4 + (r0 & 3));
  // D2 mapping: 32 K-split x 16 batch-groups of 4
  const int ktd = tid >> 4;             // 0..31
  const int cgd = tid & 15;
  float* const Gpd = &Gp[0][0][0];      // D2 alias: [32][4][68] = 34 KB

  // ---------------- init ----------------
  {
    if (tid < 256) {
      int idx = blk * 256 + tid;        // 65536 == HH*BB
      g_hA[idx]  = 0.0f;
      g_cst[idx] = 0.0f;
    }
    int r = blk * 16 + (tid >> 5);
    int l32 = tid & 31;
    const float* wrp = dWih + (size_t)r * NO;
    float s = 0.0f;
    for (int k = l32; k < NO; k += 32) s += wrp[k];
    for (int off = 16; off; off >>= 1) s += __shfl_down(s, off, 32);
    if (l32 == 0) g_dsum[r] = s;
    for (int w = blk * NTHR + tid; w < TT * NI * BB; w += NBLK * NTHR) {
      int b = w & 63;
      int tk = w >> 6;
      int k = tk & (NI - 1);
      int t = tk >> 8;
      g_xt[w] = xin[((size_t)b * TT + t) * NI + k];
    }
  }
  const float be0 = ebih[j2]          + ebhh[j2];
  const float be1 = ebih[HH + j2]     + ebhh[HH + j2];
  const float be2 = ebih[2 * HH + j2] + ebhh[2 * HH + j2];
  const float be3 = ebih[3 * HH + j2] + ebhh[3 * HH + j2];
  bar_arrive(blk); ++sync_no; bar_wait(blk, sync_no);

  const float* hc = g_hA;
  float* hn = g_hB;

  float4 ar0, ar1;
  float wr0, wr1;
  // prologue: t=0 chunk 0 (x + eWih)
  LOAD_A(g_xt);
  LOAD_W2(eWih, NI, 0);

  // ================ encoder: 512 steps ================
  for (int t = 0; t < TT; ++t) {
    float acc[8][8];
    #pragma unroll
    for (int r = 0; r < 8; ++r)
      #pragma unroll
      for (int c = 0; c < 8; ++c) acc[r][c] = 0.0f;

    STORE_LDS(0);
    for (int ch = 0; ch < 20; ++ch) {
      const int buf = ch & 1;
      // chunks 0..2 + their prefetches touch only static x/eWih -> run pre-wait;
      // chunk 4 (hc) prefetch happens at ch==3, so wait just before it.
      if (ch == 3) bar_wait(blk, sync_no);
      if (ch + 1 < 20) {
        const int c1 = ch + 1;
        if (c1 < 4) {
          LOAD_A(g_xt + ((size_t)t * NI + c1 * KT) * BB);
          LOAD_W2(eWih, NI, c1 * KT);
        } else {
          LOAD_A(hc + (size_t)(c1 * KT - NI) * BB);
          LOAD_W2(eWhh, HH, c1 * KT - NI);
        }
      }
      __syncthreads();
      FMA_CHUNK(buf);
      if (ch + 1 < 20) STORE_LDS(buf ^ 1);
    }
    // merge lane-halves (kt2 pairs) in-register
    #pragma unroll
    for (int r = 0; r < 8; ++r)
      #pragma unroll
      for (int c = 0; c < 8; ++c)
        acc[r][c] += __shfl_xor(acc[r][c], 32);
    __syncthreads();
    if (hi == 0) {
      #pragma unroll
      for (int r = 0; r < 8; ++r) {
        float4 v0 = {acc[r][0], acc[r][1], acc[r][2], acc[r][3]};
        float4 v1 = {acc[r][4], acc[r][5], acc[r][6], acc[r][7]};
        *(float4*)&Gp[ks16][rg * 8 + r][cg * 8]     = v0;
        *(float4*)&Gp[ks16][rg * 8 + r][cg * 8 + 4] = v1;
      }
    }
    __syncthreads();
    if (tid < 256) {
      float gsum[4];
      #pragma unroll
      for (int g = 0; g < 4; ++g) {
        const int rt = g * 4 + jj2;
        float s = 0.0f;
        #pragma unroll
        for (int q = 0; q < 16; ++q) s += Gp[q][rt][cb];
        gsum[g] = s;
      }
      float pi = gsum[0] + be0;
      float pf = gsum[1] + be1;
      float pg = gsum[2] + be2;
      float po = gsum[3] + be3;
      float co = g_cst[(size_t)j2 * BB + cb];
      float cn = sigf(pf) * co + sigf(pi) * tanhf(pg);
      float hv = sigf(po) * tanhf(cn);
      g_cst[(size_t)j2 * BB + cb] = cn;
      hn[(size_t)j2 * BB + cb] = hv;
    }
    // prefetch next step chunk 0 (static) before arriving
    {
      const int tn = (t + 1 < TT) ? t + 1 : t;
      LOAD_A(g_xt + (size_t)tn * NI * BB);
      LOAD_W2(eWih, NI, 0);
    }
    bar_arrive(blk); ++sync_no;
    float* tmp = (float*)hc; hc = hn; hn = tmp;
  }
  if (tid < BB) ptok[tid] = 0.0f;
  bar_wait(blk, sync_no);   // final encoder h visible; also covers ptok init

  // ================ decoder: 100 steps ================
  const float bd0 = dbih[j2]          + dbhh[j2];
  const float bd1 = dbih[HH + j2]     + dbhh[HH + j2];
  const float bd2 = dbih[2 * HH + j2] + dbhh[2 * HH + j2];
  const float bd3 = dbih[3 * HH + j2] + dbhh[3 * HH + j2];
  const float ds0 = g_dsum[j2];
  const float ds1 = g_dsum[HH + j2];
  const float ds2 = g_dsum[2 * HH + j2];
  const float ds3 = g_dsum[3 * HH + j2];
  // D1 s=0 chunk-0 prologue
  LOAD_A(hc);
  LOAD_W2(dWhh, HH, 0);

  for (int s = 0; s < NSTEPS; ++s) {
    // ---- D1: LSTM cell, K = HH ----
    float acc[8][8];
    #pragma unroll
    for (int r = 0; r < 8; ++r)
      #pragma unroll
      for (int c = 0; c < 8; ++c) acc[r][c] = 0.0f;

    STORE_LDS(0);
    for (int ch = 0; ch < 16; ++ch) {
      const int buf = ch & 1;
      if (ch + 1 < 16) {
        LOAD_A(hc + (size_t)(ch + 1) * KT * BB);
        LOAD_W2(dWhh, HH, (ch + 1) * KT);
      }
      __syncthreads();
      FMA_CHUNK(buf);
      if (ch + 1 < 16) STORE_LDS(buf ^ 1);
    }
    #pragma unroll
    for (int r = 0; r < 8; ++r)
      #pragma unroll
      for (int c = 0; c < 8; ++c)
        acc[r][c] += __shfl_xor(acc[r][c], 32);
    __syncthreads();
    if (hi == 0) {
      #pragma unroll
      for (int r = 0; r < 8; ++r) {
        float4 v0 = {acc[r][0], acc[r][1], acc[r][2], acc[r][3]};
        float4 v1 = {acc[r][4], acc[r][5], acc[r][6], acc[r][7]};
        *(float4*)&Gp[ks16][rg * 8 + r][cg * 8]     = v0;
        *(float4*)&Gp[ks16][rg * 8 + r][cg * 8 + 4] = v1;
      }
    }
    __syncthreads();
    if (tid < 256) {
      float gsum[4];
      #pragma unroll
      for (int g = 0; g < 4; ++g) {
        const int rt = g * 4 + jj2;
        float ssum = 0.0f;
        #pragma unroll
        for (int q = 0; q < 16; ++q) ssum += Gp[q][rt][cb];
        gsum[g] = ssum;
      }
      float tk = ptok[cb];
      float pi = gsum[0] + bd0 + tk * ds0;
      float pf = gsum[1] + bd1 + tk * ds1;
      float pg = gsum[2] + bd2 + tk * ds2;
      float po = gsum[3] + bd3 + tk * ds3;
      float co = g_cst[(size_t)j2 * BB + cb];
      float cn = sigf(pf) * co + sigf(pi) * tanhf(pg);
      float hv = sigf(po) * tanhf(cn);
      g_cst[(size_t)j2 * BB + cb] = cn;
      hn[(size_t)j2 * BB + cb] = hv;
    }
    // hoist D2's first fcW column (static)
    float fw0 = 0.0f;
    if (blk < 128) fw0 = fcW[(size_t)(blk * 4 + ((tid >> 6) & 3)) * HH + kkl];
    bar_arrive(blk); ++sync_no; bar_wait(blk, sync_no);
    { float* tmp = (float*)hc; hc = hn; hn = tmp; }   // hc = new h

    // ---- D2: logits = h @ fc_W^T + fc_b (blocks 0..127, 4 o-rows each) ----
    if (blk < 128) {
      float facc[4][4];
      #pragma unroll
      for (int r = 0; r < 4; ++r)
        #pragma unroll
        for (int c = 0; c < 4; ++c) facc[r][c] = 0.0f;

      float fw = fw0;
      LOAD_A(hc);
      { float* ab = &As[0][0][0];
        *(float4*)&ab[tid * 4]        = ar0;
        *(float4*)&ab[tid * 4 + 2048] = ar1;
        Wt[0][kkl][(tid >> 6) & 3] = fw; }
      for (int ch = 0; ch < 16; ++ch) {
        const int buf = ch & 1;
        if (ch + 1 < 16) {
          LOAD_A(hc + (size_t)(ch + 1) * KT * BB);
          fw = fcW[(size_t)(blk * 4 + ((tid >> 6) & 3)) * HH + (ch + 1) * KT + kkl];
        }
        __syncthreads();
        #pragma unroll
        for (int kk2 = 0; kk2 < 2; ++kk2) {
          const int kk = ktd * 2 + kk2;
          float4 a = *(const float4*)&As[buf][kk][cgd * 4];
          float4 w = *(const float4*)&Wt[buf][kk][0];
          float av[4] = {a.x, a.y, a.z, a.w};
          float wv[4] = {w.x, w.y, w.z, w.w};
          #pragma unroll
          for (int r = 0; r < 4; ++r)
            #pragma unroll
            for (int c = 0; c < 4; ++c)
              facc[r][c] = fmaf(wv[r], av[c], facc[r][c]);
        }
        if (ch + 1 < 16) {
          float* ab = &As[buf ^ 1][0][0];
          *(float4*)&ab[tid * 4]        = ar0;
          *(float4*)&ab[tid * 4 + 2048] = ar1;
          Wt[buf ^ 1][kkl][(tid >> 6) & 3] = fw;
        }
      }
      __syncthreads();
      #pragma unroll
      for (int r = 0; r < 4; ++r) {
        float4 v = {facc[r][0], facc[r][1], facc[r][2], facc[r][3]};
        *(float4*)&Gpd[ktd * 272 + r * 68 + cgd * 4] = v;
      }
      __syncthreads();
      if (tid < 256) {
        const int oo = tid >> 6, ob = tid & 63;
        float ssum = 0.0f;
        #pragma unroll
        for (int q = 0; q < 32; ++q) ssum += Gpd[q * 272 + oo * 68 + ob];
        const int o = blk * 4 + oo;
        g_logits[(size_t)o * BB + ob] = ssum + fcb[o];
      }
    }
    // prefetch next D1 chunk 0 (hc unchanged during D2/argmax)
    LOAD_A(hc);
    LOAD_W2(dWhh, HH, 0);
    bar_arrive(blk); ++sync_no; bar_wait(blk, sync_no);

    // ---- argmax (redundant per block; first-index tie-break) ----
    {
      const int q = tid >> 6, b = tid & 63;
      float bv = -3.402823466e38f; int bo = 0;
      for (int o = q * 64; o < q * 64 + 64; ++o) {
        float v = g_logits[(size_t)o * BB + b];
        if (v > bv) { bv = v; bo = o; }
      }
      avals[q][b] = bv; aidx[q][b] = bo;
    }
    __syncthreads();
    if (tid < BB) {
      float bv = avals[0][tid]; int bo = aidx[0][tid];
      #pragma unroll
      for (int q = 1; q < 8; ++q)
        if (avals[q][tid] > bv) { bv = avals[q][tid]; bo = aidx[q][tid]; }
      ptok[tid] = (float)bo;
      if (blk == 0) out[(size_t)tid * NSTEPS + s] = bo;   // int32 tokens
    }
    __syncthreads();
  }
}

extern "C" void kernel_launch(void* const* d_in, const int* in_sizes, int n_in,
                              void* d_out, int out_size, void* d_ws, size_t ws_size,
                              hipStream_t stream) {
  (void)in_sizes; (void)n_in; (void)out_size; (void)d_ws; (void)ws_size;
  const float* xin  = (const float*)d_in[0];
  const float* eWih = (const float*)d_in[1];
  const float* eWhh = (const float*)d_in[2];
  const float* ebih = (const float*)d_in[3];
  const float* ebhh = (const float*)d_in[4];
  const float* dWih = (const float*)d_in[5];
  const float* dWhh = (const float*)d_in[6];
  const float* dbih = (const float*)d_in[7];
  const float* dbhh = (const float*)d_in[8];
  const float* fcW  = (const float*)d_in[9];
  const float* fcb  = (const float*)d_in[10];
  int* out = (int*)d_out;

  reset_counter<<<1, 128, 0, stream>>>();
  seq2seq_kernel<<<NBLK, NTHR, 0, stream>>>(
      xin, eWih, eWhh, ebih, ebhh, dWih, dWhh, dbih, dbhh, fcW, fcb, out);
}

// Round 8
// 15496.880 us; speedup vs baseline: 1.8976x; 1.0478x over previous
//
#include <hip/hip_runtime.h>
#include <cstdint>
#include <cmath>

#define BB 64
#define TT 512
#define NI 256
#define HH 1024
#define NO 512
#define NSTEPS 100
#define KT 64
#define NBLK 256
#define NTHR 512
#define NCTR 64

// ---- persistent device-global state (module-owned; NOT in d_ws) ----
__device__ unsigned g_arr[(NCTR + 1) * 32];  // 64 arrival lines (128B apart) + flag line
__device__ float g_hA[HH * BB];
__device__ float g_hB[HH * BB];
__device__ float g_cst[HH * BB];
__device__ float g_dsum[4 * HH];
__device__ float g_logits[NO * BB];
__device__ float g_xt[TT * NI * BB];   // x transposed to [t][k][b]

__device__ __forceinline__ float sigf(float x) { return 1.0f / (1.0f + expf(-x)); }

// ---- agent-coherent (sc1) access via intrinsics: compiler-tracked waitcnts ----
__device__ __forceinline__ float2 ldh2(const float* p) {
  unsigned long long u = __hip_atomic_load((const unsigned long long*)p,
                                           __ATOMIC_RELAXED, __HIP_MEMORY_SCOPE_AGENT);
  union { unsigned long long u; float2 f; } c; c.u = u; return c.f;
}
__device__ __forceinline__ float ldc1(const float* p) {
  unsigned u = __hip_atomic_load((const unsigned*)p,
                                 __ATOMIC_RELAXED, __HIP_MEMORY_SCOPE_AGENT);
  union { unsigned u; float f; } c; c.u = u; return c.f;
}
__device__ __forceinline__ void stc1(float* p, float v) {
  union { float f; unsigned u; } c; c.f = v;
  __hip_atomic_store((unsigned*)p, c.u, __ATOMIC_RELAXED, __HIP_MEMORY_SCOPE_AGENT);
}

// Fence-free grid barrier. Release: every wave's sc1 stores are drained by the
// compiler's s_waitcnt vmcnt(0) before the s_barrier in bar_arrive (LLVM gfx94x
// model: vmcnt(0) == agent visibility for sc1 stores). Acquire: consumers read
// mutable data with sc1 loads (LLC-direct), so no cache inv is needed.
__device__ __forceinline__ void bar_arrive(int blk) {
  __syncthreads();
  if (threadIdx.x == 0) {
    __hip_atomic_fetch_add(&g_arr[(blk & (NCTR - 1)) * 32], 1u,
                           __ATOMIC_RELAXED, __HIP_MEMORY_SCOPE_AGENT);
  }
}

__device__ __forceinline__ void bar_wait(int blk, unsigned n) {
  if (threadIdx.x == 0) {
    if (blk == 0) {
      for (;;) {
        unsigned tot = 0;
        #pragma unroll
        for (int i = 0; i < NCTR; ++i)
          tot += __hip_atomic_load(&g_arr[i * 32], __ATOMIC_RELAXED, __HIP_MEMORY_SCOPE_AGENT);
        if (tot >= n * NBLK) break;
        __builtin_amdgcn_s_sleep(1);
      }
      __hip_atomic_store(&g_arr[NCTR * 32], n, __ATOMIC_RELAXED, __HIP_MEMORY_SCOPE_AGENT);
    } else {
      while (__hip_atomic_load(&g_arr[NCTR * 32], __ATOMIC_RELAXED, __HIP_MEMORY_SCOPE_AGENT) < n)
        __builtin_amdgcn_s_sleep(2);
    }
  }
  __syncthreads();
}

__global__ void reset_counter() {
  if (threadIdx.x <= NCTR) g_arr[threadIdx.x * 32] = 0u;
}

// A tile: 4096 floats = 512 threads x 4 float2 stripes (lane-contiguous dwordx2)
#define LOAD_A_X(asrc) \
  { ah0 = *(const float2*)&(asrc)[tid * 2]; \
    ah1 = *(const float2*)&(asrc)[tid * 2 + 1024]; \
    ah2 = *(const float2*)&(asrc)[tid * 2 + 2048]; \
    ah3 = *(const float2*)&(asrc)[tid * 2 + 3072]; }
#define LOAD_A_H(asrc) \
  { ah0 = ldh2(&(asrc)[tid * 2]); \
    ah1 = ldh2(&(asrc)[tid * 2 + 1024]); \
    ah2 = ldh2(&(asrc)[tid * 2 + 2048]); \
    ah3 = ldh2(&(asrc)[tid * 2 + 3072]); }
#define LOAD_W2(wsrc, ld, k) \
  { const float* wp = (wsrc) + (size_t)grow0 * (ld) + (k) + kkl; \
    wr0 = wp[0]; wr1 = wp[(size_t)(ld)]; }

#define STORE_LDS(bufi) \
  { float* ab = &As[bufi][0][0]; \
    *(float2*)&ab[tid * 2]        = ah0; \
    *(float2*)&ab[tid * 2 + 1024] = ah1; \
    *(float2*)&ab[tid * 2 + 2048] = ah2; \
    *(float2*)&ab[tid * 2 + 3072] = ah3; \
    float2 w2; w2.x = wr0; w2.y = wr1; \
    *(float2*)&Wt[bufi][kkl][r0] = w2; }

#define FMA_CHUNK(bufi) \
  _Pragma("unroll") \
  for (int kk2 = 0; kk2 < 2; ++kk2) { \
    const int kk = kt2 * 2 + kk2; \
    float4 a0 = *(const float4*)&As[bufi][kk][cg * 8]; \
    float4 a1 = *(const float4*)&As[bufi][kk][cg * 8 + 4]; \
    float4 w0 = *(const float4*)&Wt[bufi][kk][rg * 8]; \
    float4 w1 = *(const float4*)&Wt[bufi][kk][rg * 8 + 4]; \
    float av[8] = {a0.x, a0.y, a0.z, a0.w, a1.x, a1.y, a1.z, a1.w}; \
    float wv[8] = {w0.x, w0.y, w0.z, w0.w, w1.x, w1.y, w1.z, w1.w}; \
    _Pragma("unroll") for (int r = 0; r < 8; ++r) \
      _Pragma("unroll") for (int c = 0; c < 8; ++c) \
        acc[r][c] = fmaf(wv[r], av[c], acc[r][c]); \
  }

__global__ void __launch_bounds__(NTHR, 1)
seq2seq_kernel(const float* __restrict__ xin,
               const float* __restrict__ eWih, const float* __restrict__ eWhh,
               const float* __restrict__ ebih, const float* __restrict__ ebhh,
               const float* __restrict__ dWih, const float* __restrict__ dWhh,
               const float* __restrict__ dbih, const float* __restrict__ dbhh,
               const float* __restrict__ fcW,  const float* __restrict__ fcb,
               int* __restrict__ out)
{
  __shared__ __align__(16) float As[2][KT][BB];     // 32 KB double-buffered A
  __shared__ __align__(16) float Wt[2][KT][20];     // 10 KB double-buffered W^T
  __shared__ __align__(16) float Gp[16][17][68];    // 74 KB K-split partials
  __shared__ float avals[8][BB];
  __shared__ int   aidx[8][BB];
  __shared__ float ptok[BB];

  const int tid = threadIdx.x;
  const int blk = blockIdx.x;
  unsigned sync_no = 0;

  const int wv  = tid >> 6;
  const int ln  = tid & 63;
  const int hi  = ln >> 5;              // lane half (merged via shfl_xor 32)
  const int l5  = ln & 31;
  const int ks16 = (wv << 1) | (l5 >> 4);          // 0..15 LDS K-group
  const int kt2  = ks16 * 2 + hi;                  // 0..31 reg K-group
  const int rg  = (l5 >> 3) & 1;        // row group (x8)
  const int cg  = l5 & 7;               // batch group (x8)
  const int jj2 = (tid >> 6) & 3;
  const int cb  = tid & 63;
  const int j2  = blk * 4 + jj2;
  const int r0  = wv * 2;               // W staging rows
  const int kkl = ln;
  const int grow0 = ((r0 >> 2) * HH + blk * 4 + (r0 & 3));
  const int ktd = tid >> 4;             // D2: 0..31 K-split
  const int cgd = tid & 15;
  float* const Gpd = &Gp[0][0][0];      // D2 alias: [32][4][68]

  // ---------------- init ----------------
  {
    if (tid < 256) {
      int idx = blk * 256 + tid;        // block-owned h/c slice
      stc1(&g_hA[idx], 0.0f);           // h: coherent (cross-block read)
      g_cst[idx] = 0.0f;                // c: private, cached
    }
    int r = blk * 16 + (tid >> 5);
    int l32 = tid & 31;
    const float* wrp = dWih + (size_t)r * NO;
    float s = 0.0f;
    for (int k = l32; k < NO; k += 32) s += wrp[k];
    for (int off = 16; off; off >>= 1) s += __shfl_down(s, off, 32);
    if (l32 == 0) stc1(&g_dsum[r], s);
    for (int w = blk * NTHR + tid; w < TT * NI * BB; w += NBLK * NTHR) {
      int b = w & 63;
      int tk = w >> 6;
      int k = tk & (NI - 1);
      int t = tk >> 8;
      stc1(&g_xt[w], xin[((size_t)b * TT + t) * NI + k]);
    }
  }
  const float be0 = ebih[j2]          + ebhh[j2];
  const float be1 = ebih[HH + j2]     + ebhh[HH + j2];
  const float be2 = ebih[2 * HH + j2] + ebhh[2 * HH + j2];
  const float be3 = ebih[3 * HH + j2] + ebhh[3 * HH + j2];
  bar_arrive(blk); ++sync_no; bar_wait(blk, sync_no);

  const float* hc = g_hA;
  float* hn = g_hB;

  float2 ah0, ah1, ah2, ah3;
  float wr0, wr1;
  // prologue: t=0 chunk 0 (x + eWih; launch-invariant -> cached path)
  LOAD_A_X(g_xt);
  LOAD_W2(eWih, NI, 0);

  // ================ encoder: 512 steps ================
  for (int t = 0; t < TT; ++t) {
    float acc[8][8];
    #pragma unroll
    for (int r = 0; r < 8; ++r)
      #pragma unroll
      for (int c = 0; c < 8; ++c) acc[r][c] = 0.0f;

    STORE_LDS(0);
    for (int ch = 0; ch < 20; ++ch) {
      const int buf = ch & 1;
      // chunks 0..2 touch only static x/eWih -> run pre-wait;
      // first h prefetch (c1=4) is issued at ch==3, so wait just before it.
      if (ch == 3) bar_wait(blk, sync_no);
      if (ch + 1 < 20) {
        const int c1 = ch + 1;
        if (c1 < 4) {
          LOAD_A_X(g_xt + ((size_t)t * NI + c1 * KT) * BB);
          LOAD_W2(eWih, NI, c1 * KT);
        } else {
          LOAD_A_H(hc + (size_t)(c1 * KT - NI) * BB);
          LOAD_W2(eWhh, HH, c1 * KT - NI);
        }
      }
      __syncthreads();
      FMA_CHUNK(buf);
      if (ch + 1 < 20) STORE_LDS(buf ^ 1);
    }
    // merge lane-halves in-register
    #pragma unroll
    for (int r = 0; r < 8; ++r)
      #pragma unroll
      for (int c = 0; c < 8; ++c)
        acc[r][c] += __shfl_xor(acc[r][c], 32);
    __syncthreads();
    if (hi == 0) {
      #pragma unroll
      for (int r = 0; r < 8; ++r) {
        float4 v0 = {acc[r][0], acc[r][1], acc[r][2], acc[r][3]};
        float4 v1 = {acc[r][4], acc[r][5], acc[r][6], acc[r][7]};
        *(float4*)&Gp[ks16][rg * 8 + r][cg * 8]     = v0;
        *(float4*)&Gp[ks16][rg * 8 + r][cg * 8 + 4] = v1;
      }
    }
    __syncthreads();
    if (tid < 256) {
      float gsum[4];
      #pragma unroll
      for (int g = 0; g < 4; ++g) {
        const int rt = g * 4 + jj2;
        float s = 0.0f;
        #pragma unroll
        for (int q = 0; q < 16; ++q) s += Gp[q][rt][cb];
        gsum[g] = s;
      }
      float pi = gsum[0] + be0;
      float pf = gsum[1] + be1;
      float pg = gsum[2] + be2;
      float po = gsum[3] + be3;
      float co = g_cst[(size_t)j2 * BB + cb];
      float cn = sigf(pf) * co + sigf(pi) * tanhf(pg);
      float hv = sigf(po) * tanhf(cn);
      g_cst[(size_t)j2 * BB + cb] = cn;
      stc1(&hn[(size_t)j2 * BB + cb], hv);
    }
    // prefetch next step chunk 0 (static x/eWih) before arriving
    {
      const int tn = (t + 1 < TT) ? t + 1 : t;
      LOAD_A_X(g_xt + (size_t)tn * NI * BB);
      LOAD_W2(eWih, NI, 0);
    }
    bar_arrive(blk); ++sync_no;
    float* tmp = (float*)hc; hc = hn; hn = tmp;
  }
  if (tid < BB) ptok[tid] = 0.0f;
  bar_wait(blk, sync_no);   // final encoder h visible; covers ptok init too

  // ================ decoder: 100 steps ================
  const float bd0 = dbih[j2]          + dbhh[j2];
  const float bd1 = dbih[HH + j2]     + dbhh[HH + j2];
  const float bd2 = dbih[2 * HH + j2] + dbhh[2 * HH + j2];
  const float bd3 = dbih[3 * HH + j2] + dbhh[3 * HH + j2];
  const float ds0 = g_dsum[j2];
  const float ds1 = g_dsum[HH + j2];
  const float ds2 = g_dsum[2 * HH + j2];
  const float ds3 = g_dsum[3 * HH + j2];
  // D1 s=0 chunk-0 prologue
  LOAD_A_H(hc);
  LOAD_W2(dWhh, HH, 0);

  for (int s = 0; s < NSTEPS; ++s) {
    // ---- D1: LSTM cell, K = HH ----
    float acc[8][8];
    #pragma unroll
    for (int r = 0; r < 8; ++r)
      #pragma unroll
      for (int c = 0; c < 8; ++c) acc[r][c] = 0.0f;

    STORE_LDS(0);
    for (int ch = 0; ch < 16; ++ch) {
      const int buf = ch & 1;
      if (ch + 1 < 16) {
        LOAD_A_H(hc + (size_t)(ch + 1) * KT * BB);
        LOAD_W2(dWhh, HH, (ch + 1) * KT);
      }
      __syncthreads();
      FMA_CHUNK(buf);
      if (ch + 1 < 16) STORE_LDS(buf ^ 1);
    }
    #pragma unroll
    for (int r = 0; r < 8; ++r)
      #pragma unroll
      for (int c = 0; c < 8; ++c)
        acc[r][c] += __shfl_xor(acc[r][c], 32);
    __syncthreads();
    if (hi == 0) {
      #pragma unroll
      for (int r = 0; r < 8; ++r) {
        float4 v0 = {acc[r][0], acc[r][1], acc[r][2], acc[r][3]};
        float4 v1 = {acc[r][4], acc[r][5], acc[r][6], acc[r][7]};
        *(float4*)&Gp[ks16][rg * 8 + r][cg * 8]     = v0;
        *(float4*)&Gp[ks16][rg * 8 + r][cg * 8 + 4] = v1;
      }
    }
    __syncthreads();
    if (tid < 256) {
      float gsum[4];
      #pragma unroll
      for (int g = 0; g < 4; ++g) {
        const int rt = g * 4 + jj2;
        float ssum = 0.0f;
        #pragma unroll
        for (int q = 0; q < 16; ++q) ssum += Gp[q][rt][cb];
        gsum[g] = ssum;
      }
      float tk = ptok[cb];
      float pi = gsum[0] + bd0 + tk * ds0;
      float pf = gsum[1] + bd1 + tk * ds1;
      float pg = gsum[2] + bd2 + tk * ds2;
      float po = gsum[3] + bd3 + tk * ds3;
      float co = g_cst[(size_t)j2 * BB + cb];
      float cn = sigf(pf) * co + sigf(pi) * tanhf(pg);
      float hv = sigf(po) * tanhf(cn);
      g_cst[(size_t)j2 * BB + cb] = cn;
      stc1(&hn[(size_t)j2 * BB + cb], hv);
    }
    // hoist D2's first fcW column (static weights)
    float fw0 = 0.0f;
    if (blk < 128) fw0 = fcW[(size_t)(blk * 4 + ((tid >> 6) & 3)) * HH + kkl];
    bar_arrive(blk); ++sync_no; bar_wait(blk, sync_no);
    { float* tmp = (float*)hc; hc = hn; hn = tmp; }   // hc = new h

    // ---- D2: logits = h @ fc_W^T + fc_b (blocks 0..127, 4 o-rows each) ----
    if (blk < 128) {
      float facc[4][4];
      #pragma unroll
      for (int r = 0; r < 4; ++r)
        #pragma unroll
        for (int c = 0; c < 4; ++c) facc[r][c] = 0.0f;

      float fw = fw0;
      LOAD_A_H(hc);
      { float* ab = &As[0][0][0];
        *(float2*)&ab[tid * 2]        = ah0;
        *(float2*)&ab[tid * 2 + 1024] = ah1;
        *(float2*)&ab[tid * 2 + 2048] = ah2;
        *(float2*)&ab[tid * 2 + 3072] = ah3;
        Wt[0][kkl][(tid >> 6) & 3] = fw; }
      for (int ch = 0; ch < 16; ++ch) {
        const int buf = ch & 1;
        if (ch + 1 < 16) {
          LOAD_A_H(hc + (size_t)(ch + 1) * KT * BB);
          fw = fcW[(size_t)(blk * 4 + ((tid >> 6) & 3)) * HH + (ch + 1) * KT + kkl];
        }
        __syncthreads();
        #pragma unroll
        for (int kk2 = 0; kk2 < 2; ++kk2) {
          const int kk = ktd * 2 + kk2;
          float4 a = *(const float4*)&As[buf][kk][cgd * 4];
          float4 w = *(const float4*)&Wt[buf][kk][0];
          float av[4] = {a.x, a.y, a.z, a.w};
          float wvv[4] = {w.x, w.y, w.z, w.w};
          #pragma unroll
          for (int r = 0; r < 4; ++r)
            #pragma unroll
            for (int c = 0; c < 4; ++c)
              facc[r][c] = fmaf(wvv[r], av[c], facc[r][c]);
        }
        if (ch + 1 < 16) {
          float* ab = &As[buf ^ 1][0][0];
          *(float2*)&ab[tid * 2]        = ah0;
          *(float2*)&ab[tid * 2 + 1024] = ah1;
          *(float2*)&ab[tid * 2 + 2048] = ah2;
          *(float2*)&ab[tid * 2 + 3072] = ah3;
          Wt[buf ^ 1][kkl][(tid >> 6) & 3] = fw;
        }
      }
      __syncthreads();
      #pragma unroll
      for (int r = 0; r < 4; ++r) {
        float4 v = {facc[r][0], facc[r][1], facc[r][2], facc[r][3]};
        *(float4*)&Gpd[ktd * 272 + r * 68 + cgd * 4] = v;
      }
      __syncthreads();
      if (tid < 256) {
        const int oo = tid >> 6, ob = tid & 63;
        float ssum = 0.0f;
        #pragma unroll
        for (int q = 0; q < 32; ++q) ssum += Gpd[q * 272 + oo * 68 + ob];
        const int o = blk * 4 + oo;
        stc1(&g_logits[(size_t)o * BB + ob], ssum + fcb[o]);
      }
    }
    // prefetch next D1 chunk 0 (hc unchanged during D2/argmax)
    LOAD_A_H(hc);
    LOAD_W2(dWhh, HH, 0);
    bar_arrive(blk); ++sync_no; bar_wait(blk, sync_no);

    // ---- argmax (redundant per block; first-index tie-break) ----
    {
      const int q = tid >> 6, b = tid & 63;
      float bv = -3.402823466e38f; int bo = 0;
      #pragma unroll
      for (int g = 0; g < 4; ++g) {
        float lv[16];
        #pragma unroll
        for (int i = 0; i < 16; ++i)
          lv[i] = ldc1(&g_logits[(size_t)(q * 64 + g * 16 + i) * BB + b]);
        #pragma unroll
        for (int i = 0; i < 16; ++i)
          if (lv[i] > bv) { bv = lv[i]; bo = q * 64 + g * 16 + i; }
      }
      avals[q][b] = bv; aidx[q][b] = bo;
    }
    __syncthreads();
    if (tid < BB) {
      float bv = avals[0][tid]; int bo = aidx[0][tid];
      #pragma unroll
      for (int q = 1; q < 8; ++q)
        if (avals[q][tid] > bv) { bv = avals[q][tid]; bo = aidx[q][tid]; }
      ptok[tid] = (float)bo;
      if (blk == 0) out[(size_t)tid * NSTEPS + s] = bo;   // int32 tokens
    }
    __syncthreads();
  }
}

extern "C" void kernel_launch(void* const* d_in, const int* in_sizes, int n_in,
                              void* d_out, int out_size, void* d_ws, size_t ws_size,
                              hipStream_t stream) {
  (void)in_sizes; (void)n_in; (void)out_size; (void)d_ws; (void)ws_size;
  const float* xin  = (const float*)d_in[0];
  const float* eWih = (const float*)d_in[1];
  const float* eWhh = (const float*)d_in[2];
  const float* ebih = (const float*)d_in[3];
  const float* ebhh = (const float*)d_in[4];
  const float* dWih = (const float*)d_in[5];
  const float* dWhh = (const float*)d_in[6];
  const float* dbih = (const float*)d_in[7];
  const float* dbhh = (const float*)d_in[8];
  const float* fcW  = (const float*)d_in[9];
  const float* fcb  = (const float*)d_in[10];
  int* out = (int*)d_out;

  reset_counter<<<1, 128, 0, stream>>>();
  seq2seq_kernel<<<NBLK, NTHR, 0, stream>>>(
      xin, eWih, eWhh, ebih, ebhh, dWih, dWhh, dbih, dbhh, fcW, fcb, out);
}